// Round 1
// baseline (986.118 us; speedup 1.0000x reference)
//
#include <hip/hip_runtime.h>

#define TPTS 48
constexpr float EPS = 1e-5f;

__global__ __launch_bounds__(256, 4) void vfe_fused(
    const float* __restrict__ feat,
    const int* __restrict__ nvox,
    const float* __restrict__ w1, const float* __restrict__ b1,
    const float* __restrict__ g1, const float* __restrict__ be1,
    const float* __restrict__ m1, const float* __restrict__ v1,
    const float* __restrict__ w2, const float* __restrict__ b2,
    const float* __restrict__ g2, const float* __restrict__ be2,
    const float* __restrict__ m2, const float* __restrict__ v2,
    const float* __restrict__ w3, const float* __restrict__ b3,
    const float* __restrict__ g3, const float* __restrict__ be3,
    const float* __restrict__ m3, const float* __restrict__ v3,
    float* __restrict__ out)
{
    __shared__ float sX0[TPTS][8];     // x0 (48 x 8)
    __shared__ float sA[TPTS][32];     // x1 (48 x 32); reused as reduce buf at end
    __shared__ float sB[TPTS][128];    // x2 (48 x 128)
    __shared__ float sAgg[64];
    __shared__ float sMean[3];

    const int k   = blockIdx.x;
    const int tid = threadIdx.x;
    const int nv  = nvox[k];

    // ---- stage 0: load features, mean over ALL 48 rows (reference semantics), build x0 ----
    if (tid < TPTS) {
        const float4 f = *reinterpret_cast<const float4*>(feat + ((size_t)k*TPTS + tid)*4);
        sX0[tid][0]=f.x; sX0[tid][1]=f.y; sX0[tid][2]=f.z; sX0[tid][3]=f.w;
    }
    __syncthreads();
    if (tid < 3) {
        float s = 0.f;
        for (int t = 0; t < TPTS; ++t) s += sX0[t][tid];
        sMean[tid] = s / (float)nv;     // divide by num_voxels, sum over all T
    }
    __syncthreads();
    if (tid < TPTS) {
        const float x=sX0[tid][0], y=sX0[tid][1], z=sX0[tid][2], w=sX0[tid][3];
        const float msk = (tid < nv) ? 1.f : 0.f;
        const float d = sqrtf(x*x + y*y + z*z);   // norm of raw xyz
        sX0[tid][0]=x*msk; sX0[tid][1]=y*msk; sX0[tid][2]=z*msk; sX0[tid][3]=w*msk;
        sX0[tid][4]=(x - sMean[0])*msk;
        sX0[tid][5]=(y - sMean[1])*msk;
        sX0[tid][6]=(z - sMean[2])*msk;
        sX0[tid][7]=d*msk;
    }
    __syncthreads();

    // ---- layer 1: (48x8)@(8x16) + BN + relu ----
    {
        const int u = tid & 15, tb = tid >> 4;   // 16 u x 16 tb = 256 threads
        float wr[8];
        #pragma unroll
        for (int c = 0; c < 8; ++c) wr[c] = w1[c*16 + u];
        const float s  = g1[u]*rsqrtf(v1[u]+EPS);
        const float cc = be1[u] - m1[u]*s;
        const float bb = b1[u];
        #pragma unroll
        for (int j = 0; j < 3; ++j) {
            const int t = tb + j*16;
            float acc = bb;
            #pragma unroll
            for (int c = 0; c < 8; ++c) acc += sX0[t][c]*wr[c];
            sA[t][u] = fmaxf(acc*s + cc, 0.f);    // unmasked h1 (agg sees these)
        }
    }
    __syncthreads();
    if (tid < 16) {
        float mx = -1e30f;
        for (int t = 0; t < TPTS; ++t) mx = fmaxf(mx, sA[t][tid]);
        sAgg[tid] = mx;
    }
    __syncthreads();
    {   // x1 = [h1, agg1] * mask
        const int u = tid & 15, tb = tid >> 4;
        #pragma unroll
        for (int j = 0; j < 3; ++j) {
            const int t = tb + j*16;
            const float msk = (t < nv) ? 1.f : 0.f;
            sA[t][u]      *= msk;
            sA[t][16 + u]  = sAgg[u]*msk;
        }
    }
    __syncthreads();

    // ---- layer 2: (48x32)@(32x64) + BN + relu ----
    {
        const int u = tid & 63, tb = tid >> 6;   // tb 0..3, 12 t-rows each
        float wr[32];
        #pragma unroll
        for (int c = 0; c < 32; ++c) wr[c] = w2[c*64 + u];
        const float s  = g2[u]*rsqrtf(v2[u]+EPS);
        const float cc = be2[u] - m2[u]*s;
        const float bb = b2[u];
        #pragma unroll
        for (int j = 0; j < 12; ++j) {
            const int t = tb + j*4;
            float acc = bb;
            #pragma unroll
            for (int c = 0; c < 32; c += 4) {
                const float4 xv = *reinterpret_cast<const float4*>(&sA[t][c]);
                acc += xv.x*wr[c] + xv.y*wr[c+1] + xv.z*wr[c+2] + xv.w*wr[c+3];
            }
            sB[t][u] = fmaxf(acc*s + cc, 0.f);    // unmasked h2
        }
    }
    __syncthreads();
    if (tid < 64) {
        float mx = -1e30f;
        for (int t = 0; t < TPTS; ++t) mx = fmaxf(mx, sB[t][tid]);
        sAgg[tid] = mx;
    }
    __syncthreads();
    {   // x2 = [h2, agg2] * mask
        const int u = tid & 63, tb = tid >> 6;
        #pragma unroll
        for (int j = 0; j < 12; ++j) {
            const int t = tb + j*4;
            const float msk = (t < nv) ? 1.f : 0.f;
            sB[t][u]      *= msk;
            sB[t][64 + u]  = sAgg[u]*msk;
        }
    }
    __syncthreads();

    // ---- layer 3: (48x128)@(128x128) + BN + relu + max over t ----
    {
        const int u  = tid & 127;
        const int th = tid >> 7;      // 0/1, each half handles 24 t-rows
        const int t0 = th*24;
        float acc[24];
        #pragma unroll
        for (int j = 0; j < 24; ++j) acc[j] = 0.f;

        for (int c = 0; c < 128; c += 4) {
            const float wq0 = w3[(c+0)*128 + u];
            const float wq1 = w3[(c+1)*128 + u];
            const float wq2 = w3[(c+2)*128 + u];
            const float wq3 = w3[(c+3)*128 + u];
            #pragma unroll
            for (int j = 0; j < 24; ++j) {
                const float4 xv = *reinterpret_cast<const float4*>(&sB[t0 + j][c]);
                acc[j] += xv.x*wq0 + xv.y*wq1 + xv.z*wq2 + xv.w*wq3;
            }
        }

        const float s  = g3[u]*rsqrtf(v3[u]+EPS);
        const float cc = be3[u] - m3[u]*s;
        const float bb = b3[u];
        float mx = 0.f;   // relu >= 0 and masked rows are 0, so 0 is a valid identity
        const int tlim = nv - t0;
        #pragma unroll
        for (int j = 0; j < 24; ++j) {
            if (j < tlim) {
                const float h = fmaxf((acc[j] + bb)*s + cc, 0.f);
                mx = fmaxf(mx, h);
            }
        }

        float* sRed = &sA[0][0];      // reuse sA as 128-float reduce buffer
        if (th == 0) sRed[u] = mx;
        __syncthreads();
        if (th == 1) out[(size_t)k*128 + u] = fmaxf(mx, sRed[u]);
    }
}

extern "C" void kernel_launch(void* const* d_in, const int* in_sizes, int n_in,
                              void* d_out, int out_size, void* d_ws, size_t ws_size,
                              hipStream_t stream) {
    const float* feat = (const float*)d_in[0];
    const int*   nvx  = (const int*)d_in[1];
    // d_in[2] = coors (unused by reference output)
    const float* w1 = (const float*)d_in[3];
    const float* b1 = (const float*)d_in[4];
    const float* g1 = (const float*)d_in[5];
    const float* be1= (const float*)d_in[6];
    const float* m1 = (const float*)d_in[7];
    const float* v1 = (const float*)d_in[8];
    const float* w2 = (const float*)d_in[9];
    const float* b2 = (const float*)d_in[10];
    const float* g2 = (const float*)d_in[11];
    const float* be2= (const float*)d_in[12];
    const float* m2 = (const float*)d_in[13];
    const float* v2 = (const float*)d_in[14];
    const float* w3 = (const float*)d_in[15];
    const float* b3 = (const float*)d_in[16];
    const float* g3 = (const float*)d_in[17];
    const float* be3= (const float*)d_in[18];
    const float* m3 = (const float*)d_in[19];
    const float* v3 = (const float*)d_in[20];
    float* out = (float*)d_out;

    const int K = in_sizes[1];   // 30000 voxels
    vfe_fused<<<K, 256, 0, stream>>>(feat, nvx,
        w1,b1,g1,be1,m1,v1, w2,b2,g2,be2,m2,v2, w3,b3,g3,be3,m3,v3, out);
}

// Round 2
// 124.330 us; speedup vs baseline: 7.9314x; 7.9314x over previous
//
#include <hip/hip_runtime.h>

#define TPTS 48
constexpr float EPS = 1e-5f;

typedef __attribute__((ext_vector_type(8))) short bf16x8;
typedef __attribute__((ext_vector_type(4))) float f32x4;

// d_ws layout (bytes):
//   0      : w3p  - 16384 bf16 (fragment-packed, BN-scale folded)  32768 B
//   32768  : w2p  -  2048 bf16 (fragment-packed, BN-scale folded)   4096 B
//   36864  : w1f  -   128 f32  (w1 * s1)                             512 B
//   37376  : bias1-    16 f32  ((b-m)*s+be)
//   37440  : bias2-    64 f32
//   37696  : bias3-   128 f32
#define W2P_OFF 32768
#define W1F_OFF 36864
#define B1_OFF  37376
#define B2_OFF  37440
#define B3_OFF  37696

__device__ __forceinline__ ushort f2bf(float x) {
    union { float f; unsigned u; } a; a.f = x;
    unsigned r = a.u + 0x7fffu + ((a.u >> 16) & 1u);   // RTNE
    return (ushort)(r >> 16);
}

// Pre-fold BN into weights; pack w2/w3 into per-lane fragment order so each
// B-fragment is a single 16B coalesced load. k->slot map: k = ks*32 + g*8 + e
// (same bijection used for A fragments in the main kernel, so any HW K-perm cancels).
__global__ void vfe_prep(
    const float* __restrict__ w1, const float* __restrict__ b1,
    const float* __restrict__ g1, const float* __restrict__ be1,
    const float* __restrict__ m1, const float* __restrict__ v1,
    const float* __restrict__ w2, const float* __restrict__ b2,
    const float* __restrict__ g2, const float* __restrict__ be2,
    const float* __restrict__ m2, const float* __restrict__ v2,
    const float* __restrict__ w3, const float* __restrict__ b3,
    const float* __restrict__ g3, const float* __restrict__ be3,
    const float* __restrict__ m3, const float* __restrict__ v3,
    void* __restrict__ ws)
{
    ushort* w3p = (ushort*)ws;
    ushort* w2p = (ushort*)((char*)ws + W2P_OFF);
    float*  w1f = (float*)((char*)ws + W1F_OFF);
    float*  bb1 = (float*)((char*)ws + B1_OFF);
    float*  bb2 = (float*)((char*)ws + B2_OFF);
    float*  bb3 = (float*)((char*)ws + B3_OFF);

    const int i = blockIdx.x * 256 + threadIdx.x;
    if (i < 16384) {                       // w3p: ((nt*4+ks)*64 + lane)*8 + e
        const int e = i & 7, l = (i >> 3) & 63, rest = i >> 9;
        const int ks = rest & 3, nt = rest >> 2, g = l >> 4;
        const int k = ks * 32 + g * 8 + e;
        const int n = nt * 16 + (l & 15);
        const float s = g3[n] * rsqrtf(v3[n] + EPS);
        w3p[i] = f2bf(w3[k * 128 + n] * s);
    } else if (i < 18432) {                // w2p: (nt*64 + lane)*8 + e
        const int j = i - 16384;
        const int e = j & 7, l = (j >> 3) & 63, nt = j >> 9, g = l >> 4;
        const int k = g * 8 + e;
        const int n = nt * 16 + (l & 15);
        const float s = g2[n] * rsqrtf(v2[n] + EPS);
        w2p[j] = f2bf(w2[k * 64 + n] * s);
    } else if (i < 18768) {
        const int j = i - 18432;
        if (j < 128) {
            const int u = j & 15;
            w1f[j] = w1[j] * (g1[u] * rsqrtf(v1[u] + EPS));
        } else if (j < 144) {
            const int u = j - 128;
            bb1[u] = (b1[u] - m1[u]) * (g1[u] * rsqrtf(v1[u] + EPS)) + be1[u];
        } else if (j < 208) {
            const int u = j - 144;
            bb2[u] = (b2[u] - m2[u]) * (g2[u] * rsqrtf(v2[u] + EPS)) + be2[u];
        } else {
            const int u = j - 208;
            bb3[u] = (b3[u] - m3[u]) * (g3[u] * rsqrtf(v3[u] + EPS)) + be3[u];
        }
    }
}

__global__ __launch_bounds__(256, 3) void vfe_fused(
    const float* __restrict__ feat,
    const int* __restrict__ nvox,
    const void* __restrict__ ws,
    float* __restrict__ out)
{
    __shared__ __align__(16) float  sX0[TPTS][8];
    __shared__ __align__(16) float  sH1[TPTS][16];
    __shared__ __align__(16) ushort sA[TPTS][32];     // x1 bf16
    __shared__ __align__(16) ushort sB[TPTS * 128];   // x2 bf16, XOR-swizzled
    __shared__ float sAgg[16];
    __shared__ float sP[4][16];
    __shared__ float sMean[3];

    const ushort* w3p = (const ushort*)ws;
    const ushort* w2p = (const ushort*)((const char*)ws + W2P_OFF);
    const float*  w1f = (const float*)((const char*)ws + W1F_OFF);
    const float*  bb1 = (const float*)((const char*)ws + B1_OFF);
    const float*  bb2 = (const float*)((const char*)ws + B2_OFF);
    const float*  bb3 = (const float*)((const char*)ws + B3_OFF);

    const int k    = blockIdx.x;
    const int tid  = threadIdx.x;
    const int nv   = nvox[k];
    const int lane = tid & 63;
    const int w    = tid >> 6;       // wave id 0..3
    const int g    = lane >> 4;      // lane group 0..3
    const int m15  = lane & 15;

    // ---- preload B fragments (L2-hot, hidden under stages 0-2) ----
    const bf16x8 b2f = *(const bf16x8*)(w2p + (size_t)(w * 64 + lane) * 8);
    bf16x8 b3f[2][4];
    #pragma unroll
    for (int n2 = 0; n2 < 2; ++n2)
        #pragma unroll
        for (int ks = 0; ks < 4; ++ks)
            b3f[n2][ks] = *(const bf16x8*)(w3p + (size_t)(((w * 2 + n2) * 4 + ks) * 64 + lane) * 8);

    // ---- stage 0: features -> x0 (mean over ALL 48 rows / nv; mask after) ----
    if (tid < TPTS) {
        const float4 f = *reinterpret_cast<const float4*>(feat + ((size_t)k * TPTS + tid) * 4);
        sX0[tid][0] = f.x; sX0[tid][1] = f.y; sX0[tid][2] = f.z; sX0[tid][3] = f.w;
    }
    __syncthreads();
    if (tid < 3) {
        float s = 0.f;
        for (int t = 0; t < TPTS; ++t) s += sX0[t][tid];
        sMean[tid] = s / (float)nv;
    }
    __syncthreads();
    if (tid < TPTS) {
        const float x = sX0[tid][0], y = sX0[tid][1], z = sX0[tid][2], ww = sX0[tid][3];
        const float msk = (tid < nv) ? 1.f : 0.f;
        const float d = sqrtf(x * x + y * y + z * z);
        sX0[tid][0] = x * msk; sX0[tid][1] = y * msk; sX0[tid][2] = z * msk; sX0[tid][3] = ww * msk;
        sX0[tid][4] = (x - sMean[0]) * msk;
        sX0[tid][5] = (y - sMean[1]) * msk;
        sX0[tid][6] = (z - sMean[2]) * msk;
        sX0[tid][7] = d * msk;
    }
    __syncthreads();

    // ---- layer 1 (fp32, BN folded): h1 = relu(x0 @ w1f + bias1), unmasked ----
    {
        const int u = tid & 15, tb = tid >> 4;
        float wr[8];
        #pragma unroll
        for (int c = 0; c < 8; ++c) wr[c] = w1f[c * 16 + u];
        const float bia = bb1[u];
        #pragma unroll
        for (int j = 0; j < 3; ++j) {
            const int t = tb + j * 16;
            float acc = bia;
            #pragma unroll
            for (int c = 0; c < 8; ++c) acc += sX0[t][c] * wr[c];
            sH1[t][u] = fmaxf(acc, 0.f);
        }
    }
    __syncthreads();
    // agg1: column max over 48 rows (two-step)
    if (tid < 64) {
        const int u = tid & 15, gg = tid >> 4;
        float mx = 0.f;
        #pragma unroll
        for (int j = 0; j < 12; ++j) mx = fmaxf(mx, sH1[gg * 12 + j][u]);
        sP[gg][u] = mx;
    }
    __syncthreads();
    if (tid < 16)
        sAgg[tid] = fmaxf(fmaxf(sP[0][tid], sP[1][tid]), fmaxf(sP[2][tid], sP[3][tid]));
    __syncthreads();
    // x1 = [h1, agg1] * mask -> bf16
    #pragma unroll
    for (int it = 0; it < 6; ++it) {
        const int i = tid + it * 256;          // 1536 = 48*32
        const int t = i >> 5, c = i & 31;
        const float val = (t < nv) ? (c < 16 ? sH1[t][c] : sAgg[c - 16]) : 0.f;
        sA[t][c] = f2bf(val);
    }
    __syncthreads();

    // ---- layer 2 MFMA: (48x32)@(32x64), wave w owns cols [16w,16w+16) ----
    f32x4 acc2[3];
    #pragma unroll
    for (int mt = 0; mt < 3; ++mt) { acc2[mt].x = 0.f; acc2[mt].y = 0.f; acc2[mt].z = 0.f; acc2[mt].w = 0.f; }
    #pragma unroll
    for (int mt = 0; mt < 3; ++mt) {
        const bf16x8 af = *(const bf16x8*)&sA[mt * 16 + m15][g * 8];
        acc2[mt] = __builtin_amdgcn_mfma_f32_16x16x32_bf16(af, b2f, acc2[mt], 0, 0, 0);
    }
    {
        const int col = w * 16 + m15;
        const float bia = bb2[col];
        float h2v[3][4];
        float mx2 = 0.f;
        #pragma unroll
        for (int mt = 0; mt < 3; ++mt)
            #pragma unroll
            for (int r = 0; r < 4; ++r) {
                const float h = fmaxf(acc2[mt][r] + bia, 0.f);
                h2v[mt][r] = h;
                mx2 = fmaxf(mx2, h);
            }
        mx2 = fmaxf(mx2, __shfl_xor(mx2, 16));
        mx2 = fmaxf(mx2, __shfl_xor(mx2, 32));   // agg2 over all 48 (unmasked) rows

        // x2[t][0:64] = h2*mask ; x2[t][64:128] = agg2*mask  (bf16, swizzled)
        char* sBb = (char*)sB;
        #pragma unroll
        for (int mt = 0; mt < 3; ++mt)
            #pragma unroll
            for (int r = 0; r < 4; ++r) {
                const int row = mt * 16 + g * 4 + r;
                const float val = (row < nv) ? h2v[mt][r] : 0.f;
                const int off = row * 256 + ((col * 2) ^ ((row & 7) << 4));
                *(ushort*)(sBb + off) = f2bf(val);
            }
        #pragma unroll
        for (int j = 0; j < 12; ++j) {
            const int row = g * 12 + j;
            const float val = (row < nv) ? mx2 : 0.f;
            const int off = row * 256 + (((64 + col) * 2) ^ ((row & 7) << 4));
            *(ushort*)(sBb + off) = f2bf(val);
        }
    }
    __syncthreads();

    // ---- layer 3 MFMA: (48x128)@(128x128), wave w owns cols [32w,32w+32) ----
    f32x4 acc3[3][2];
    #pragma unroll
    for (int mt = 0; mt < 3; ++mt)
        #pragma unroll
        for (int n2 = 0; n2 < 2; ++n2) {
            acc3[mt][n2].x = 0.f; acc3[mt][n2].y = 0.f; acc3[mt][n2].z = 0.f; acc3[mt][n2].w = 0.f;
        }
    {
        const char* sBb = (const char*)sB;
        #pragma unroll
        for (int mt = 0; mt < 3; ++mt) {
            const int row = mt * 16 + m15;
            bf16x8 af[4];
            #pragma unroll
            for (int ks = 0; ks < 4; ++ks) {
                const int colb = (ks * 64 + g * 16) ^ ((row & 7) << 4);
                af[ks] = *(const bf16x8*)(sBb + row * 256 + colb);
            }
            #pragma unroll
            for (int n2 = 0; n2 < 2; ++n2)
                #pragma unroll
                for (int ks = 0; ks < 4; ++ks)
                    acc3[mt][n2] = __builtin_amdgcn_mfma_f32_16x16x32_bf16(af[ks], b3f[n2][ks], acc3[mt][n2], 0, 0, 0);
        }
    }
    // epilogue: relu(acc + bias3) -> masked max over t -> out
    #pragma unroll
    for (int n2 = 0; n2 < 2; ++n2) {
        const int col = (w * 2 + n2) * 16 + m15;
        const float bia = bb3[col];
        float mxo = 0.f;
        #pragma unroll
        for (int mt = 0; mt < 3; ++mt)
            #pragma unroll
            for (int r = 0; r < 4; ++r) {
                const int row = mt * 16 + g * 4 + r;
                const float h = fmaxf(acc3[mt][n2][r] + bia, 0.f);
                mxo = fmaxf(mxo, (row < nv) ? h : 0.f);
            }
        mxo = fmaxf(mxo, __shfl_xor(mxo, 16));
        mxo = fmaxf(mxo, __shfl_xor(mxo, 32));
        if (g == n2) out[(size_t)k * 128 + col] = mxo;
    }
}

extern "C" void kernel_launch(void* const* d_in, const int* in_sizes, int n_in,
                              void* d_out, int out_size, void* d_ws, size_t ws_size,
                              hipStream_t stream) {
    const float* feat = (const float*)d_in[0];
    const int*   nvx  = (const int*)d_in[1];
    const float* w1 = (const float*)d_in[3];
    const float* b1 = (const float*)d_in[4];
    const float* g1 = (const float*)d_in[5];
    const float* be1= (const float*)d_in[6];
    const float* m1 = (const float*)d_in[7];
    const float* v1 = (const float*)d_in[8];
    const float* w2 = (const float*)d_in[9];
    const float* b2 = (const float*)d_in[10];
    const float* g2 = (const float*)d_in[11];
    const float* be2= (const float*)d_in[12];
    const float* m2 = (const float*)d_in[13];
    const float* v2 = (const float*)d_in[14];
    const float* w3 = (const float*)d_in[15];
    const float* b3 = (const float*)d_in[16];
    const float* g3 = (const float*)d_in[17];
    const float* be3= (const float*)d_in[18];
    const float* m3 = (const float*)d_in[19];
    const float* v3 = (const float*)d_in[20];
    float* out = (float*)d_out;

    const int K = in_sizes[1];

    vfe_prep<<<74, 256, 0, stream>>>(w1,b1,g1,be1,m1,v1, w2,b2,g2,be2,m2,v2,
                                     w3,b3,g3,be3,m3,v3, d_ws);
    vfe_fused<<<K, 256, 0, stream>>>(feat, nvx, d_ws, out);
}

// Round 3
// 97.398 us; speedup vs baseline: 10.1247x; 1.2765x over previous
//
#include <hip/hip_runtime.h>
#include <hip/hip_bf16.h>

constexpr float EPS = 1e-5f;

typedef __attribute__((ext_vector_type(8))) short bf16x8;
typedef __attribute__((ext_vector_type(4))) float f32x4;

// d_ws layout (bytes):
//   0      : w3p  - 16384 bf16 (fragment-packed, BN-scale folded)
//   32768  : w2p  -  2048 bf16 (fragment-packed, BN-scale folded)
//   36864  : w1f  -   128 f32  (w1 * s1)
//   37376  : bias1-    16 f32
//   37440  : bias2-    64 f32
//   37696  : bias3-   128 f32
#define W2P_OFF 32768
#define W1F_OFF 36864
#define B1_OFF  37376
#define B2_OFF  37440
#define B3_OFF  37696

__device__ __forceinline__ ushort f2bf(float x) {
    __hip_bfloat16 h = __float2bfloat16(x);   // RTNE; compiler emits v_cvt_pk_bf16_f32
    return *reinterpret_cast<ushort*>(&h);
}

// Pack weights into per-lane MFMA fragment order, BN scale folded.
// k -> slot map: k = ks*32 + g*8 + e (same bijection as A-side, so HW K-perm cancels).
__global__ void vfe_prep(
    const float* __restrict__ w1, const float* __restrict__ b1,
    const float* __restrict__ g1, const float* __restrict__ be1,
    const float* __restrict__ m1, const float* __restrict__ v1,
    const float* __restrict__ w2, const float* __restrict__ b2,
    const float* __restrict__ g2, const float* __restrict__ be2,
    const float* __restrict__ m2, const float* __restrict__ v2,
    const float* __restrict__ w3, const float* __restrict__ b3,
    const float* __restrict__ g3, const float* __restrict__ be3,
    const float* __restrict__ m3, const float* __restrict__ v3,
    void* __restrict__ ws)
{
    ushort* w3p = (ushort*)ws;
    ushort* w2p = (ushort*)((char*)ws + W2P_OFF);
    float*  w1f = (float*)((char*)ws + W1F_OFF);
    float*  bb1 = (float*)((char*)ws + B1_OFF);
    float*  bb2 = (float*)((char*)ws + B2_OFF);
    float*  bb3 = (float*)((char*)ws + B3_OFF);

    const int i = blockIdx.x * 256 + threadIdx.x;
    if (i < 16384) {                       // w3p: ((nt*4+ks)*64 + lane)*8 + e
        const int e = i & 7, l = (i >> 3) & 63, rest = i >> 9;
        const int ks = rest & 3, nt = rest >> 2, g = l >> 4;
        const int k = ks * 32 + g * 8 + e;
        const int n = nt * 16 + (l & 15);
        const float s = g3[n] * rsqrtf(v3[n] + EPS);
        w3p[i] = f2bf(w3[k * 128 + n] * s);
    } else if (i < 18432) {                // w2p: (nt*64 + lane)*8 + e
        const int j = i - 16384;
        const int e = j & 7, l = (j >> 3) & 63, nt = j >> 9, g = l >> 4;
        const int k = g * 8 + e;
        const int n = nt * 16 + (l & 15);
        const float s = g2[n] * rsqrtf(v2[n] + EPS);
        w2p[j] = f2bf(w2[k * 64 + n] * s);
    } else if (i < 18768) {
        const int j = i - 18432;
        if (j < 128) {
            const int u = j & 15;
            w1f[j] = w1[j] * (g1[u] * rsqrtf(v1[u] + EPS));
        } else if (j < 144) {
            const int u = j - 128;
            bb1[u] = (b1[u] - m1[u]) * (g1[u] * rsqrtf(v1[u] + EPS)) + be1[u];
        } else if (j < 208) {
            const int u = j - 144;
            bb2[u] = (b2[u] - m2[u]) * (g2[u] * rsqrtf(v2[u] + EPS)) + be2[u];
        } else {
            const int u = j - 208;
            bb3[u] = (b3[u] - m3[u]) * (g3[u] * rsqrtf(v3[u] + EPS)) + be3[u];
        }
    }
}

// 2 voxels per block, 256 threads / 4 waves. Rows 0-47 = voxel A, 48-95 = voxel B.
__global__ __launch_bounds__(256, 3) void vfe_fused(
    const float* __restrict__ feat,
    const int* __restrict__ nvox,
    const void* __restrict__ ws,
    float* __restrict__ out,
    int K)
{
    __shared__ float  sX0[96][9];                       // x0, pad 9 -> conflict-free L1 reads
    __shared__ __align__(16) ushort sAfrag[6*4*16*8];   // x1, A-fragment order
    __shared__ __align__(16) ushort sBfrag[6*2*64*8];   // h2 (64 cols), A-fragment order
    __shared__ float  sP[16][17];                       // layer-1 partial col-max
    __shared__ float  sAgg1[2][16];
    __shared__ __align__(16) ushort sAgg2bf[2][64];
    __shared__ float  sZ[2][128];                       // agg2 . w3s[64:] per voxel

    const ushort* w3p = (const ushort*)ws;
    const ushort* w2p = (const ushort*)((const char*)ws + W2P_OFF);
    const float*  w1f = (const float*)((const char*)ws + W1F_OFF);
    const float*  bb1 = (const float*)((const char*)ws + B1_OFF);
    const float*  bb2 = (const float*)((const char*)ws + B2_OFF);
    const float*  bb3 = (const float*)((const char*)ws + B3_OFF);

    const int tid  = threadIdx.x;
    const int lane = tid & 63;
    const int w    = tid >> 6;
    const int g    = lane >> 4;
    const int m15  = lane & 15;
    const int kA   = blockIdx.x * 2;
    const int kB   = kA + 1;
    const bool hasB = (kB < K);
    const int nvA  = nvox[kA];
    const int nvB  = hasB ? nvox[kB] : 1;

    // ---- B-fragment preloads (L2-hot, overlap with stages below) ----
    const bf16x8 b2f = *(const bf16x8*)(w2p + (size_t)(w*64 + lane)*8);
    bf16x8 b3f[2][4];
    #pragma unroll
    for (int nt = 0; nt < 2; ++nt)
        #pragma unroll
        for (int ks = 0; ks < 4; ++ks)
            b3f[nt][ks] = *(const bf16x8*)(w3p + (size_t)(((w*2+nt)*4+ks)*64 + lane)*8);

    // ---- stage 0: wave 0 -> voxel A, wave 1 -> voxel B; mean via shfl reduce ----
    if (w < 2) {
        const int vox = w;
        const int nv  = vox ? nvB : nvA;
        const int kk  = vox ? kB : kA;
        float4 f = make_float4(0.f, 0.f, 0.f, 0.f);
        if (lane < 48 && (vox == 0 || hasB))
            f = *reinterpret_cast<const float4*>(feat + ((size_t)kk*48 + lane)*4);
        float sx = f.x, sy = f.y, sz = f.z;   // lanes >= 48 contribute 0
        #pragma unroll
        for (int d = 1; d < 64; d <<= 1) {
            sx += __shfl_xor(sx, d);
            sy += __shfl_xor(sy, d);
            sz += __shfl_xor(sz, d);
        }
        const float inv = 1.f / (float)nv;
        if (lane < 48) {
            const float msk = (lane < nv) ? 1.f : 0.f;
            const float dd = sqrtf(f.x*f.x + f.y*f.y + f.z*f.z);
            const int r = vox*48 + lane;
            sX0[r][0] = f.x*msk; sX0[r][1] = f.y*msk;
            sX0[r][2] = f.z*msk; sX0[r][3] = f.w*msk;
            sX0[r][4] = (f.x - sx*inv)*msk;
            sX0[r][5] = (f.y - sy*inv)*msk;
            sX0[r][6] = (f.z - sz*inv)*msk;
            sX0[r][7] = dd*msk;
        }
    }
    __syncthreads();

    // ---- layer 1 (fp32): h1 -> sAfrag (masked bf16) + partial col-max ----
    {
        const int u = tid & 15, tb = tid >> 4;
        const int vox = tb >> 3;
        const int nv  = vox ? nvB : nvA;
        const int t0  = vox*48 + (tb & 7)*6;
        float wr[8];
        #pragma unroll
        for (int c = 0; c < 8; ++c) wr[c] = w1f[c*16 + u];
        const float bia = bb1[u];
        const int gp = u >> 3, e = u & 7;
        float pmax = 0.f;
        #pragma unroll
        for (int j = 0; j < 6; ++j) {
            const int t = t0 + j;
            float acc = bia;
            #pragma unroll
            for (int c = 0; c < 8; ++c) acc += sX0[t][c]*wr[c];
            const float h = fmaxf(acc, 0.f);     // rows>=nv give relu(bias) automatically
            pmax = fmaxf(pmax, h);
            const int tl = (tb & 7)*6 + j;
            sAfrag[(((t >> 4)*4 + gp)*16 + (t & 15))*8 + e] = f2bf(tl < nv ? h : 0.f);
        }
        sP[u][tb] = pmax;
    }
    __syncthreads();
    if (tid < 32) {
        const int u = tid & 15, vox = tid >> 4;
        float mx = 0.f;
        #pragma unroll
        for (int tb = 0; tb < 8; ++tb) mx = fmaxf(mx, sP[u][vox*8 + tb]);
        sAgg1[vox][u] = mx;
    }
    __syncthreads();
    // agg half of x1 (cols 16-31), masked
    #pragma unroll
    for (int it = 0; it < 6; ++it) {
        const int i = tid + it*256;            // 1536 = 96*16
        const int t = i >> 4, cc = i & 15;
        const int vox = (t >= 48);
        const int tl  = t - vox*48;
        const int nv  = vox ? nvB : nvA;
        const float val = (tl < nv) ? sAgg1[vox][cc] : 0.f;
        sAfrag[(((t >> 4)*4 + 2 + (cc >> 3))*16 + (t & 15))*8 + (cc & 7)] = f2bf(val);
    }
    __syncthreads();

    // ---- layer 2 MFMA: (96x32)@(32x64); wave w owns cols [16w,16w+16) ----
    f32x4 acc2[6];
    #pragma unroll
    for (int mt = 0; mt < 6; ++mt) acc2[mt] = (f32x4){0.f,0.f,0.f,0.f};
    #pragma unroll
    for (int mt = 0; mt < 6; ++mt) {
        const bf16x8 af = *(const bf16x8*)&sAfrag[((mt*4 + g)*16 + m15)*8];
        acc2[mt] = __builtin_amdgcn_mfma_f32_16x16x32_bf16(af, b2f, acc2[mt], 0, 0, 0);
    }
    {
        const int col = w*16 + m15;
        const float bia = bb2[col];
        const int ks = col >> 5, gp = (col >> 3) & 3, e = col & 7;
        float mxA = 0.f, mxB = 0.f;
        #pragma unroll
        for (int mt = 0; mt < 6; ++mt) {
            const int vox = (mt >= 3);
            const int nv  = vox ? nvB : nvA;
            const int tb  = (mt - vox*3)*16 + g*4;
            #pragma unroll
            for (int r = 0; r < 4; ++r) {
                const float h = fmaxf(acc2[mt][r] + bia, 0.f);   // rows>=nv = relu(bb2): in agg
                if (vox) mxB = fmaxf(mxB, h); else mxA = fmaxf(mxA, h);
                sBfrag[((mt*2 + ks)*64 + gp*16 + (g*4 + r))*8 + e] = f2bf((tb + r) < nv ? h : 0.f);
            }
        }
        mxA = fmaxf(mxA, __shfl_xor(mxA, 16));
        mxA = fmaxf(mxA, __shfl_xor(mxA, 32));
        mxB = fmaxf(mxB, __shfl_xor(mxB, 16));
        mxB = fmaxf(mxB, __shfl_xor(mxB, 32));
        if (g == 0) {
            sAgg2bf[0][col] = f2bf(mxA);
            sAgg2bf[1][col] = f2bf(mxB);
        }
    }
    __syncthreads();

    // ---- aggdot: z[vox][n] = agg2 . w3s[64:128] via tiny MFMA (C rows 0/1) ----
    f32x4 zacc[2];
    #pragma unroll
    for (int nt = 0; nt < 2; ++nt) zacc[nt] = (f32x4){0.f,0.f,0.f,0.f};
    #pragma unroll
    for (int ks2 = 0; ks2 < 2; ++ks2) {
        const bf16x8 af = *(const bf16x8*)&sAgg2bf[m15 & 1][ks2*32 + g*8]; // rows>=2 dup, C rows>=2 unread
        #pragma unroll
        for (int nt = 0; nt < 2; ++nt)
            zacc[nt] = __builtin_amdgcn_mfma_f32_16x16x32_bf16(af, b3f[nt][2+ks2], zacc[nt], 0, 0, 0);
    }
    if (g == 0) {
        #pragma unroll
        for (int nt = 0; nt < 2; ++nt) {
            const int col = (w*2 + nt)*16 + m15;
            sZ[0][col] = zacc[nt][0];   // C row 0 = voxel A
            sZ[1][col] = zacc[nt][1];   // C row 1 = voxel B
        }
    }

    // ---- layer 3 MFMA: (96x64)@(64x128); wave w owns cols [32w,32w+32) ----
    f32x4 acc3[6][2];
    #pragma unroll
    for (int mt = 0; mt < 6; ++mt)
        #pragma unroll
        for (int nt = 0; nt < 2; ++nt) acc3[mt][nt] = (f32x4){0.f,0.f,0.f,0.f};
    #pragma unroll
    for (int mt = 0; mt < 6; ++mt) {
        const bf16x8 af0 = *(const bf16x8*)&sBfrag[((mt*2 + 0)*64 + lane)*8];
        const bf16x8 af1 = *(const bf16x8*)&sBfrag[((mt*2 + 1)*64 + lane)*8];
        #pragma unroll
        for (int nt = 0; nt < 2; ++nt) {
            acc3[mt][nt] = __builtin_amdgcn_mfma_f32_16x16x32_bf16(af0, b3f[nt][0], acc3[mt][nt], 0, 0, 0);
            acc3[mt][nt] = __builtin_amdgcn_mfma_f32_16x16x32_bf16(af1, b3f[nt][1], acc3[mt][nt], 0, 0, 0);
        }
    }
    __syncthreads();   // sZ visible

    // ---- epilogue: relu(acc + bias + z) -> masked max over rows -> out ----
    #pragma unroll
    for (int nt = 0; nt < 2; ++nt) {
        const int col = (w*2 + nt)*16 + m15;
        const float bA = bb3[col] + sZ[0][col];
        const float bB = bb3[col] + sZ[1][col];
        float mxA = 0.f, mxB = 0.f;
        #pragma unroll
        for (int mt = 0; mt < 3; ++mt) {
            #pragma unroll
            for (int r = 0; r < 4; ++r) {
                const int tl = mt*16 + g*4 + r;
                const float hA = fmaxf(acc3[mt][nt][r] + bA, 0.f);
                if (tl < nvA) mxA = fmaxf(mxA, hA);
                const float hB = fmaxf(acc3[mt+3][nt][r] + bB, 0.f);
                if (tl < nvB) mxB = fmaxf(mxB, hB);
            }
        }
        mxA = fmaxf(mxA, __shfl_xor(mxA, 16));
        mxA = fmaxf(mxA, __shfl_xor(mxA, 32));
        mxB = fmaxf(mxB, __shfl_xor(mxB, 16));
        mxB = fmaxf(mxB, __shfl_xor(mxB, 32));
        if (g == 0) out[(size_t)kA*128 + col] = mxA;
        if (g == 1 && hasB) out[(size_t)kB*128 + col] = mxB;
    }
}

extern "C" void kernel_launch(void* const* d_in, const int* in_sizes, int n_in,
                              void* d_out, int out_size, void* d_ws, size_t ws_size,
                              hipStream_t stream) {
    const float* feat = (const float*)d_in[0];
    const int*   nvx  = (const int*)d_in[1];
    const float* w1 = (const float*)d_in[3];
    const float* b1 = (const float*)d_in[4];
    const float* g1 = (const float*)d_in[5];
    const float* be1= (const float*)d_in[6];
    const float* m1 = (const float*)d_in[7];
    const float* v1 = (const float*)d_in[8];
    const float* w2 = (const float*)d_in[9];
    const float* b2 = (const float*)d_in[10];
    const float* g2 = (const float*)d_in[11];
    const float* be2= (const float*)d_in[12];
    const float* m2 = (const float*)d_in[13];
    const float* v2 = (const float*)d_in[14];
    const float* w3 = (const float*)d_in[15];
    const float* b3 = (const float*)d_in[16];
    const float* g3 = (const float*)d_in[17];
    const float* be3= (const float*)d_in[18];
    const float* m3 = (const float*)d_in[19];
    const float* v3 = (const float*)d_in[20];
    float* out = (float*)d_out;

    const int K = in_sizes[1];

    vfe_prep<<<74, 256, 0, stream>>>(w1,b1,g1,be1,m1,v1, w2,b2,g2,be2,m2,v2,
                                     w3,b3,g3,be3,m3,v3, d_ws);
    vfe_fused<<<(K + 1) / 2, 256, 0, stream>>>(feat, nvx, d_ws, out, K);
}

// Round 6
// 92.310 us; speedup vs baseline: 10.6826x; 1.0551x over previous
//
#include <hip/hip_runtime.h>
#include <hip/hip_bf16.h>

constexpr float EPS = 1e-5f;

typedef __attribute__((ext_vector_type(8))) short bf16x8;
typedef __attribute__((ext_vector_type(4))) float f32x4;

// d_ws layout (bytes):
//   0      : w3p  - 16384 bf16 (fragment-packed, BN-scale folded)
//   32768  : w2p  -  2048 bf16 (fragment-packed, BN-scale folded)
//   36864  : w1f  -   128 f32  (w1 * s1)
//   37376  : bias1-    16 f32
//   37440  : bias2-    64 f32
//   37696  : bias3-   128 f32
#define W2P_OFF 32768
#define W1F_OFF 36864
#define B1_OFF  37376
#define B2_OFF  37440
#define B3_OFF  37696

__device__ __forceinline__ ushort f2bf(float x) {
    __hip_bfloat16 h = __float2bfloat16(x);   // RTNE; validated in R2
    return *reinterpret_cast<ushort*>(&h);
}

// Pack weights into per-lane MFMA fragment order, BN scale folded.
// k -> slot map: k = ks*32 + g*8 + e (same bijection as A-side staging).
__global__ void vfe_prep(
    const float* __restrict__ w1, const float* __restrict__ b1,
    const float* __restrict__ g1, const float* __restrict__ be1,
    const float* __restrict__ m1, const float* __restrict__ v1,
    const float* __restrict__ w2, const float* __restrict__ b2,
    const float* __restrict__ g2, const float* __restrict__ be2,
    const float* __restrict__ m2, const float* __restrict__ v2,
    const float* __restrict__ w3, const float* __restrict__ b3,
    const float* __restrict__ g3, const float* __restrict__ be3,
    const float* __restrict__ m3, const float* __restrict__ v3,
    void* __restrict__ ws)
{
    ushort* w3p = (ushort*)ws;
    ushort* w2p = (ushort*)((char*)ws + W2P_OFF);
    float*  w1f = (float*)((char*)ws + W1F_OFF);
    float*  bb1 = (float*)((char*)ws + B1_OFF);
    float*  bb2 = (float*)((char*)ws + B2_OFF);
    float*  bb3 = (float*)((char*)ws + B3_OFF);

    const int i = blockIdx.x * 256 + threadIdx.x;
    if (i < 16384) {                       // w3p: ((nt*4+ks)*64 + l)*8 + e
        const int e = i & 7, l = (i >> 3) & 63, rest = i >> 9;
        const int ks = rest & 3, nt = rest >> 2, g = l >> 4;
        const int k = ks * 32 + g * 8 + e;
        const int n = nt * 16 + (l & 15);
        const float s = g3[n] * rsqrtf(v3[n] + EPS);
        w3p[i] = f2bf(w3[k * 128 + n] * s);
    } else if (i < 18432) {                // w2p: (nt*64 + l)*8 + e
        const int j = i - 16384;
        const int e = j & 7, l = (j >> 3) & 63, nt = j >> 9, g = l >> 4;
        const int k = g * 8 + e;
        const int n = nt * 16 + (l & 15);
        const float s = g2[n] * rsqrtf(v2[n] + EPS);
        w2p[j] = f2bf(w2[k * 64 + n] * s);
    } else if (i < 18768) {
        const int j = i - 18432;
        if (j < 128) {
            const int u = j & 15;
            w1f[j] = w1[j] * (g1[u] * rsqrtf(v1[u] + EPS));
        } else if (j < 144) {
            const int u = j - 128;
            bb1[u] = (b1[u] - m1[u]) * (g1[u] * rsqrtf(v1[u] + EPS)) + be1[u];
        } else if (j < 208) {
            const int u = j - 144;
            bb2[u] = (b2[u] - m2[u]) * (g2[u] * rsqrtf(v2[u] + EPS)) + be2[u];
        } else {
            const int u = j - 208;
            bb3[u] = (b3[u] - m3[u]) * (g3[u] * rsqrtf(v3[u] + EPS)) + be3[u];
        }
    }
}

// 2 voxels per block, 256 threads / 4 waves. Rows 0-47 = voxel A, 48-95 = voxel B.
__global__ __launch_bounds__(256, 3) void vfe_fused(
    const float* __restrict__ feat,
    const int* __restrict__ nvox,
    const void* __restrict__ ws,
    float* __restrict__ out,
    int K)
{
    __shared__ float  sX0[96][9];
    __shared__ __align__(16) ushort sAfrag[6*4*16*8];   // x1, A-fragment order
    __shared__ __align__(16) ushort sBfrag[6*2*64*8];   // h2, A-fragment order
    __shared__ float  sP[16][17];
    __shared__ float  sAgg1[2][16];
    __shared__ __align__(16) ushort sAgg2bf[2][64];
    __shared__ float  sZ[2][128];

    const ushort* w3p = (const ushort*)ws;
    const ushort* w2p = (const ushort*)((const char*)ws + W2P_OFF);
    const float*  w1f = (const float*)((const char*)ws + W1F_OFF);
    const float*  bb1 = (const float*)((const char*)ws + B1_OFF);
    const float*  bb2 = (const float*)((const char*)ws + B2_OFF);
    const float*  bb3 = (const float*)((const char*)ws + B3_OFF);

    const int tid  = threadIdx.x;
    const int lane = tid & 63;
    const int w    = tid >> 6;
    const int g    = lane >> 4;
    const int m15  = lane & 15;
    const int kA   = blockIdx.x * 2;
    const int kB   = kA + 1;
    const bool hasB = (kB < K);
    int nvA = nvox[kA];
    nvA = __builtin_amdgcn_readfirstlane(nvA);
    int nvB = hasB ? nvox[kB] : 1;
    nvB = __builtin_amdgcn_readfirstlane(nvB);
    const int limA = (nvA + 15) >> 4;      // 1..3, block-uniform (nv in [1,47])
    const int limB = (nvB + 15) >> 4;

    // ---- B-fragment preloads (L2-hot, overlap with stages below) ----
    const bf16x8 b2f = *(const bf16x8*)(w2p + (size_t)(w*64 + lane)*8);
    bf16x8 b3f[2][4];
    #pragma unroll
    for (int nt = 0; nt < 2; ++nt)
        #pragma unroll
        for (int ks = 0; ks < 4; ++ks)
            b3f[nt][ks] = *(const bf16x8*)(w3p + (size_t)(((w*2+nt)*4+ks)*64 + lane)*8);

    // ---- stage 0: wave 0 -> voxel A, wave 1 -> voxel B; mean via shfl reduce ----
    if (w < 2) {
        const int vox = w;
        const int nv  = vox ? nvB : nvA;
        const int kk  = vox ? kB : kA;
        float4 f = make_float4(0.f, 0.f, 0.f, 0.f);
        if (lane < 48 && (vox == 0 || hasB))
            f = *reinterpret_cast<const float4*>(feat + ((size_t)kk*48 + lane)*4);
        float sx = f.x, sy = f.y, sz = f.z;
        #pragma unroll
        for (int d = 1; d < 64; d <<= 1) {
            sx += __shfl_xor(sx, d);
            sy += __shfl_xor(sy, d);
            sz += __shfl_xor(sz, d);
        }
        const float inv = 1.f / (float)nv;
        if (lane < 48) {
            const float msk = (lane < nv) ? 1.f : 0.f;
            const float dd = sqrtf(f.x*f.x + f.y*f.y + f.z*f.z);
            const int r = vox*48 + lane;
            sX0[r][0] = f.x*msk; sX0[r][1] = f.y*msk;
            sX0[r][2] = f.z*msk; sX0[r][3] = f.w*msk;
            sX0[r][4] = (f.x - sx*inv)*msk;
            sX0[r][5] = (f.y - sy*inv)*msk;
            sX0[r][6] = (f.z - sz*inv)*msk;
            sX0[r][7] = dd*msk;
        }
    }
    __syncthreads();

    // ---- layer 1 (fp32): h1 -> sAfrag (masked bf16) + partial col-max (predicated) ----
    {
        const int u = tid & 15, tb = tid >> 4;
        const int vox = tb >> 3;
        const int nv   = vox ? nvB : nvA;
        const int limV = vox ? limB : limA;
        const int t0  = vox*48 + (tb & 7)*6;
        float wr[8];
        #pragma unroll
        for (int c = 0; c < 8; ++c) wr[c] = w1f[c*16 + u];
        const float bia = bb1[u];
        const int gp = u >> 3, e = u & 7;
        float pmax = 0.f;
        #pragma unroll
        for (int j = 0; j < 6; ++j) {
            const int tl = (tb & 7)*6 + j;
            if (tl < limV*16) {
                const int t = t0 + j;
                float acc = bia;
                #pragma unroll
                for (int c = 0; c < 8; ++c) acc += sX0[t][c]*wr[c];
                const float h = fmaxf(acc, 0.f);
                pmax = fmaxf(pmax, h);
                sAfrag[(((t >> 4)*4 + gp)*16 + (t & 15))*8 + e] = f2bf(tl < nv ? h : 0.f);
            }
        }
        sP[u][tb] = pmax;
    }
    __syncthreads();
    if (tid < 32) {
        const int u = tid & 15, vox = tid >> 4;
        float mx = fmaxf(bb1[u], 0.f);     // analytic masked-row term (nv<48 always holds)
        #pragma unroll
        for (int tb = 0; tb < 8; ++tb) mx = fmaxf(mx, sP[u][vox*8 + tb]);
        sAgg1[vox][u] = mx;
    }
    __syncthreads();
    // agg half of x1 (cols 16-31), masked, predicated to live tiles
    #pragma unroll
    for (int it = 0; it < 6; ++it) {
        const int i = tid + it*256;            // 1536 = 96*16
        const int t = i >> 4, cc = i & 15;
        const int vox = (t >= 48);
        const int tl  = t - vox*48;
        const int nv   = vox ? nvB : nvA;
        const int limV = vox ? limB : limA;
        if (tl < limV*16) {
            const float val = (tl < nv) ? sAgg1[vox][cc] : 0.f;
            sAfrag[(((t >> 4)*4 + 2 + (cc >> 3))*16 + (t & 15))*8 + (cc & 7)] = f2bf(val);
        }
    }
    __syncthreads();

    // ---- layer 2 MFMA: (96x32)@(32x64); wave w owns cols [16w,16w+16) ----
    f32x4 acc2[6];
    #pragma unroll
    for (int mt = 0; mt < 6; ++mt) acc2[mt] = (f32x4){0.f,0.f,0.f,0.f};
    #pragma unroll
    for (int mt = 0; mt < 6; ++mt) {
        const int vox = (mt >= 3);
        const int limV = vox ? limB : limA;
        if ((mt - vox*3) < limV) {
            const bf16x8 af = *(const bf16x8*)&sAfrag[((mt*4 + g)*16 + m15)*8];
            acc2[mt] = __builtin_amdgcn_mfma_f32_16x16x32_bf16(af, b2f, acc2[mt], 0, 0, 0);
        }
    }
    {
        const int col = w*16 + m15;
        const float bia = bb2[col];
        const int ks = col >> 5, gp = (col >> 3) & 3, e = col & 7;
        float mxA = fmaxf(bia, 0.f);       // analytic masked-row term
        float mxB = fmaxf(bia, 0.f);
        #pragma unroll
        for (int mt = 0; mt < 6; ++mt) {
            const int vox = (mt >= 3);
            const int nv   = vox ? nvB : nvA;
            const int limV = vox ? limB : limA;
            const int mtl = mt - vox*3;
            if (mtl < limV) {
                const int tb = mtl*16 + g*4;
                #pragma unroll
                for (int r = 0; r < 4; ++r) {
                    const float h = fmaxf(acc2[mt][r] + bia, 0.f);
                    if (vox) mxB = fmaxf(mxB, h); else mxA = fmaxf(mxA, h);
                    sBfrag[((mt*2 + ks)*64 + gp*16 + (g*4 + r))*8 + e] = f2bf((tb + r) < nv ? h : 0.f);
                }
            }
        }
        mxA = fmaxf(mxA, __shfl_xor(mxA, 16));
        mxA = fmaxf(mxA, __shfl_xor(mxA, 32));
        mxB = fmaxf(mxB, __shfl_xor(mxB, 16));
        mxB = fmaxf(mxB, __shfl_xor(mxB, 32));
        if (g == 0) {
            sAgg2bf[0][col] = f2bf(mxA);
            sAgg2bf[1][col] = f2bf(mxB);
        }
    }
    __syncthreads();

    // ---- aggdot: z[vox][n] = agg2 . w3s[64:128] via tiny MFMA (C rows 0/1) ----
    f32x4 zacc[2];
    #pragma unroll
    for (int nt = 0; nt < 2; ++nt) zacc[nt] = (f32x4){0.f,0.f,0.f,0.f};
    #pragma unroll
    for (int ks2 = 0; ks2 < 2; ++ks2) {
        const bf16x8 af = *(const bf16x8*)&sAgg2bf[m15 & 1][ks2*32 + g*8];
        #pragma unroll
        for (int nt = 0; nt < 2; ++nt)
            zacc[nt] = __builtin_amdgcn_mfma_f32_16x16x32_bf16(af, b3f[nt][2+ks2], zacc[nt], 0, 0, 0);
    }
    if (g == 0) {
        #pragma unroll
        for (int nt = 0; nt < 2; ++nt) {
            const int col = (w*2 + nt)*16 + m15;
            sZ[0][col] = zacc[nt][0];   // C row 0 = voxel A
            sZ[1][col] = zacc[nt][1];   // C row 1 = voxel B
        }
    }

    // ---- layer 3 MFMA: (96x64)@(64x128); wave w owns cols [32w,32w+32) ----
    f32x4 acc3[6][2];
    #pragma unroll
    for (int mt = 0; mt < 6; ++mt)
        #pragma unroll
        for (int nt = 0; nt < 2; ++nt) acc3[mt][nt] = (f32x4){0.f,0.f,0.f,0.f};
    #pragma unroll
    for (int mt = 0; mt < 6; ++mt) {
        const int vox = (mt >= 3);
        const int limV = vox ? limB : limA;
        if ((mt - vox*3) < limV) {
            const bf16x8 af0 = *(const bf16x8*)&sBfrag[((mt*2 + 0)*64 + lane)*8];
            const bf16x8 af1 = *(const bf16x8*)&sBfrag[((mt*2 + 1)*64 + lane)*8];
            #pragma unroll
            for (int nt = 0; nt < 2; ++nt) {
                acc3[mt][nt] = __builtin_amdgcn_mfma_f32_16x16x32_bf16(af0, b3f[nt][0], acc3[mt][nt], 0, 0, 0);
                acc3[mt][nt] = __builtin_amdgcn_mfma_f32_16x16x32_bf16(af1, b3f[nt][1], acc3[mt][nt], 0, 0, 0);
            }
        }
    }
    __syncthreads();   // sZ visible

    // ---- epilogue: relu(acc + bias + z) -> masked max over rows -> out ----
    #pragma unroll
    for (int nt = 0; nt < 2; ++nt) {
        const int col = (w*2 + nt)*16 + m15;
        const float bA = bb3[col] + sZ[0][col];
        const float bB = bb3[col] + sZ[1][col];
        float mxA = 0.f, mxB = 0.f;
        #pragma unroll
        for (int mt = 0; mt < 3; ++mt) {
            if (mt < limA) {
                #pragma unroll
                for (int r = 0; r < 4; ++r) {
                    const int tl = mt*16 + g*4 + r;
                    const float hA = fmaxf(acc3[mt][nt][r] + bA, 0.f);
                    if (tl < nvA) mxA = fmaxf(mxA, hA);
                }
            }
            if (mt < limB) {
                #pragma unroll
                for (int r = 0; r < 4; ++r) {
                    const int tl = mt*16 + g*4 + r;
                    const float hB = fmaxf(acc3[mt+3][nt][r] + bB, 0.f);
                    if (tl < nvB) mxB = fmaxf(mxB, hB);
                }
            }
        }
        mxA = fmaxf(mxA, __shfl_xor(mxA, 16));
        mxA = fmaxf(mxA, __shfl_xor(mxA, 32));
        mxB = fmaxf(mxB, __shfl_xor(mxB, 16));
        mxB = fmaxf(mxB, __shfl_xor(mxB, 32));
        if (g == 0) out[(size_t)kA*128 + col] = mxA;
        if (g == 1 && hasB) out[(size_t)kB*128 + col] = mxB;
    }
}

extern "C" void kernel_launch(void* const* d_in, const int* in_sizes, int n_in,
                              void* d_out, int out_size, void* d_ws, size_t ws_size,
                              hipStream_t stream) {
    const float* feat = (const float*)d_in[0];
    const int*   nvx  = (const int*)d_in[1];
    const float* w1 = (const float*)d_in[3];
    const float* b1 = (const float*)d_in[4];
    const float* g1 = (const float*)d_in[5];
    const float* be1= (const float*)d_in[6];
    const float* m1 = (const float*)d_in[7];
    const float* v1 = (const float*)d_in[8];
    const float* w2 = (const float*)d_in[9];
    const float* b2 = (const float*)d_in[10];
    const float* g2 = (const float*)d_in[11];
    const float* be2= (const float*)d_in[12];
    const float* m2 = (const float*)d_in[13];
    const float* v2 = (const float*)d_in[14];
    const float* w3 = (const float*)d_in[15];
    const float* b3 = (const float*)d_in[16];
    const float* g3 = (const float*)d_in[17];
    const float* be3= (const float*)d_in[18];
    const float* m3 = (const float*)d_in[19];
    const float* v3 = (const float*)d_in[20];
    float* out = (float*)d_out;

    const int K = in_sizes[1];

    vfe_prep<<<74, 256, 0, stream>>>(w1,b1,g1,be1,m1,v1, w2,b2,g2,be2,m2,v2,
                                     w3,b3,g3,be3,m3,v3, d_ws);
    vfe_fused<<<(K + 1) / 2, 256, 0, stream>>>(feat, nvx, d_ws, out, K);
}

// Round 7
// 86.529 us; speedup vs baseline: 11.3964x; 1.0668x over previous
//
#include <hip/hip_runtime.h>
#include <hip/hip_bf16.h>

constexpr float EPS = 1e-5f;

typedef __attribute__((ext_vector_type(8))) short bf16x8;
typedef __attribute__((ext_vector_type(4))) float f32x4;

// d_ws layout (bytes):
//   0      : w3p  - 16384 bf16 (fragment-packed, BN-scale folded)
//   32768  : w2p  -  2048 bf16 (fragment-packed, BN-scale folded)
//   36864  : w1f  -   128 f32  (w1 * s1)
//   37376  : bias1-    16 f32
//   37440  : bias2-    64 f32
//   37696  : bias3-   128 f32
#define W2P_OFF 32768
#define W1F_OFF 36864
#define B1_OFF  37376
#define B2_OFF  37440
#define B3_OFF  37696

__device__ __forceinline__ ushort f2bf(float x) {
    __hip_bfloat16 h = __float2bfloat16(x);   // RTNE
    return *reinterpret_cast<ushort*>(&h);
}

// Pack weights into per-lane MFMA fragment order, BN scale folded.
// k -> slot map: k = ks*32 + g*8 + e (same bijection as A-side staging).
__global__ void vfe_prep(
    const float* __restrict__ w1, const float* __restrict__ b1,
    const float* __restrict__ g1, const float* __restrict__ be1,
    const float* __restrict__ m1, const float* __restrict__ v1,
    const float* __restrict__ w2, const float* __restrict__ b2,
    const float* __restrict__ g2, const float* __restrict__ be2,
    const float* __restrict__ m2, const float* __restrict__ v2,
    const float* __restrict__ w3, const float* __restrict__ b3,
    const float* __restrict__ g3, const float* __restrict__ be3,
    const float* __restrict__ m3, const float* __restrict__ v3,
    void* __restrict__ ws)
{
    ushort* w3p = (ushort*)ws;
    ushort* w2p = (ushort*)((char*)ws + W2P_OFF);
    float*  w1f = (float*)((char*)ws + W1F_OFF);
    float*  bb1 = (float*)((char*)ws + B1_OFF);
    float*  bb2 = (float*)((char*)ws + B2_OFF);
    float*  bb3 = (float*)((char*)ws + B3_OFF);

    const int i = blockIdx.x * 256 + threadIdx.x;
    if (i < 16384) {                       // w3p: ((nt*4+ks)*64 + l)*8 + e
        const int e = i & 7, l = (i >> 3) & 63, rest = i >> 9;
        const int ks = rest & 3, nt = rest >> 2, g = l >> 4;
        const int k = ks * 32 + g * 8 + e;
        const int n = nt * 16 + (l & 15);
        const float s = g3[n] * rsqrtf(v3[n] + EPS);
        w3p[i] = f2bf(w3[k * 128 + n] * s);
    } else if (i < 18432) {                // w2p: (nt*64 + l)*8 + e
        const int j = i - 16384;
        const int e = j & 7, l = (j >> 3) & 63, nt = j >> 9, g = l >> 4;
        const int k = g * 8 + e;
        const int n = nt * 16 + (l & 15);
        const float s = g2[n] * rsqrtf(v2[n] + EPS);
        w2p[j] = f2bf(w2[k * 64 + n] * s);
    } else if (i < 18768) {
        const int j = i - 18432;
        if (j < 128) {
            const int u = j & 15;
            w1f[j] = w1[j] * (g1[u] * rsqrtf(v1[u] + EPS));
        } else if (j < 144) {
            const int u = j - 128;
            bb1[u] = (b1[u] - m1[u]) * (g1[u] * rsqrtf(v1[u] + EPS)) + be1[u];
        } else if (j < 208) {
            const int u = j - 144;
            bb2[u] = (b2[u] - m2[u]) * (g2[u] * rsqrtf(v2[u] + EPS)) + be2[u];
        } else {
            const int u = j - 208;
            bb3[u] = (b3[u] - m3[u]) * (g3[u] * rsqrtf(v3[u] + EPS)) + be3[u];
        }
    }
}

// 2 voxels per block, 256 threads / 4 waves. Rows 0-47 = voxel A, 48-95 = voxel B.
__global__ __launch_bounds__(256, 4) void vfe_fused(
    const float* __restrict__ feat,
    const int* __restrict__ nvox,
    const void* __restrict__ ws,
    float* __restrict__ out,
    int K)
{
    __shared__ __align__(16) float  sX0[96][8];         // stride 8 -> float4-aligned rows
    __shared__ __align__(16) ushort sAfrag[6*4*16*8];   // x1, A-fragment order
    __shared__ __align__(16) ushort sBfrag[6*2*64*8];   // h2, A-fragment order
    __shared__ float  sP[16][17];
    __shared__ float  sAgg1[2][16];
    __shared__ __align__(16) ushort sAgg2bf[2][64];
    __shared__ float  sZ[2][128];

    const ushort* w3p = (const ushort*)ws;
    const ushort* w2p = (const ushort*)((const char*)ws + W2P_OFF);
    const float*  w1f = (const float*)((const char*)ws + W1F_OFF);
    const float*  bb1 = (const float*)((const char*)ws + B1_OFF);
    const float*  bb2 = (const float*)((const char*)ws + B2_OFF);
    const float*  bb3 = (const float*)((const char*)ws + B3_OFF);

    const int tid  = threadIdx.x;
    const int lane = tid & 63;
    const int w    = tid >> 6;
    const int g    = lane >> 4;
    const int m15  = lane & 15;
    const int kA   = blockIdx.x * 2;
    const int kB   = kA + 1;
    const bool hasB = (kB < K);
    int nvA = nvox[kA];
    nvA = __builtin_amdgcn_readfirstlane(nvA);
    int nvB = hasB ? nvox[kB] : 1;
    nvB = __builtin_amdgcn_readfirstlane(nvB);
    const int limA = (nvA + 15) >> 4;      // 1..3, block-uniform (nv in [1,47])
    const int limB = (nvB + 15) >> 4;

    // ---- B-fragment preloads (L2-hot, overlap with stages below) ----
    const bf16x8 b2f = *(const bf16x8*)(w2p + (size_t)(w*64 + lane)*8);
    bf16x8 b3f[2][4];
    #pragma unroll
    for (int nt = 0; nt < 2; ++nt)
        #pragma unroll
        for (int ks = 0; ks < 4; ++ks)
            b3f[nt][ks] = *(const bf16x8*)(w3p + (size_t)(((w*2+nt)*4+ks)*64 + lane)*8);

    // ---- stage 0: wave 0 -> voxel A, wave 1 -> voxel B; mean via shfl reduce ----
    if (w < 2) {
        const int vox = w;
        const int nv  = vox ? nvB : nvA;
        const int kk  = vox ? kB : kA;
        float4 f = make_float4(0.f, 0.f, 0.f, 0.f);
        if (lane < 48 && (vox == 0 || hasB))
            f = *reinterpret_cast<const float4*>(feat + ((size_t)kk*48 + lane)*4);
        float sx = f.x, sy = f.y, sz = f.z;
        #pragma unroll
        for (int d = 1; d < 64; d <<= 1) {
            sx += __shfl_xor(sx, d);
            sy += __shfl_xor(sy, d);
            sz += __shfl_xor(sz, d);
        }
        const float inv = 1.f / (float)nv;
        if (lane < 48) {
            const float msk = (lane < nv) ? 1.f : 0.f;
            const float dd = sqrtf(f.x*f.x + f.y*f.y + f.z*f.z);
            const int r = vox*48 + lane;
            float4* row = reinterpret_cast<float4*>(&sX0[r][0]);
            row[0] = make_float4(f.x*msk, f.y*msk, f.z*msk, f.w*msk);
            row[1] = make_float4((f.x - sx*inv)*msk, (f.y - sy*inv)*msk,
                                 (f.z - sz*inv)*msk, dd*msk);
        }
    }
    __syncthreads();

    // ---- layer 1 (fp32): h1 -> sAfrag (masked bf16) + partial col-max (predicated) ----
    {
        const int u = tid & 15, tb = tid >> 4;
        const int vox = tb >> 3;
        const int nv   = vox ? nvB : nvA;
        const int limV = vox ? limB : limA;
        const int t0  = vox*48 + (tb & 7)*6;
        float wr[8];
        #pragma unroll
        for (int c = 0; c < 8; ++c) wr[c] = w1f[c*16 + u];
        const float bia = bb1[u];
        const int gp = u >> 3, e = u & 7;
        float pmax = 0.f;
        #pragma unroll
        for (int j = 0; j < 6; ++j) {
            const int tl = (tb & 7)*6 + j;
            if (tl < limV*16) {
                const int t = t0 + j;
                const float4 xv0 = *reinterpret_cast<const float4*>(&sX0[t][0]);
                const float4 xv1 = *reinterpret_cast<const float4*>(&sX0[t][4]);
                float acc = bia;
                acc += xv0.x*wr[0] + xv0.y*wr[1] + xv0.z*wr[2] + xv0.w*wr[3];
                acc += xv1.x*wr[4] + xv1.y*wr[5] + xv1.z*wr[6] + xv1.w*wr[7];
                const float h = fmaxf(acc, 0.f);
                pmax = fmaxf(pmax, h);
                sAfrag[(((t >> 4)*4 + gp)*16 + (t & 15))*8 + e] = f2bf(tl < nv ? h : 0.f);
            }
        }
        sP[u][tb] = pmax;
    }
    __syncthreads();
    if (tid < 32) {
        const int u = tid & 15, vox = tid >> 4;
        float mx = fmaxf(bb1[u], 0.f);     // analytic masked-row term (nv<48 always holds)
        #pragma unroll
        for (int tb = 0; tb < 8; ++tb) mx = fmaxf(mx, sP[u][vox*8 + tb]);
        sAgg1[vox][u] = mx;
    }
    __syncthreads();
    // agg half of x1 (cols 16-31), masked, predicated to live tiles
    #pragma unroll
    for (int it = 0; it < 6; ++it) {
        const int i = tid + it*256;            // 1536 = 96*16
        const int t = i >> 4, cc = i & 15;
        const int vox = (t >= 48);
        const int tl  = t - vox*48;
        const int nv   = vox ? nvB : nvA;
        const int limV = vox ? limB : limA;
        if (tl < limV*16) {
            const float val = (tl < nv) ? sAgg1[vox][cc] : 0.f;
            sAfrag[(((t >> 4)*4 + 2 + (cc >> 3))*16 + (t & 15))*8 + (cc & 7)] = f2bf(val);
        }
    }
    __syncthreads();

    // ---- layer 2 MFMA: (96x32)@(32x64); wave w owns cols [16w,16w+16) ----
    f32x4 acc2[6];
    #pragma unroll
    for (int mt = 0; mt < 6; ++mt) acc2[mt] = (f32x4){0.f,0.f,0.f,0.f};
    #pragma unroll
    for (int mt = 0; mt < 6; ++mt) {
        const int vox = (mt >= 3);
        const int limV = vox ? limB : limA;
        if ((mt - vox*3) < limV) {
            const bf16x8 af = *(const bf16x8*)&sAfrag[((mt*4 + g)*16 + m15)*8];
            acc2[mt] = __builtin_amdgcn_mfma_f32_16x16x32_bf16(af, b2f, acc2[mt], 0, 0, 0);
        }
    }
    {
        const int col = w*16 + m15;
        const float bia = bb2[col];
        const int ks = col >> 5, gp = (col >> 3) & 3, e = col & 7;
        float mxA = fmaxf(bia, 0.f);       // analytic masked-row term
        float mxB = fmaxf(bia, 0.f);
        #pragma unroll
        for (int mt = 0; mt < 6; ++mt) {
            const int vox = (mt >= 3);
            const int nv   = vox ? nvB : nvA;
            const int limV = vox ? limB : limA;
            const int mtl = mt - vox*3;
            if (mtl < limV) {
                const int tb = mtl*16 + g*4;
                #pragma unroll
                for (int r = 0; r < 4; ++r) {
                    const float h = fmaxf(acc2[mt][r] + bia, 0.f);
                    if (vox) mxB = fmaxf(mxB, h); else mxA = fmaxf(mxA, h);
                    sBfrag[((mt*2 + ks)*64 + gp*16 + (g*4 + r))*8 + e] = f2bf((tb + r) < nv ? h : 0.f);
                }
            }
        }
        mxA = fmaxf(mxA, __shfl_xor(mxA, 16));
        mxA = fmaxf(mxA, __shfl_xor(mxA, 32));
        mxB = fmaxf(mxB, __shfl_xor(mxB, 16));
        mxB = fmaxf(mxB, __shfl_xor(mxB, 32));
        if (g == 0) {
            sAgg2bf[0][col] = f2bf(mxA);
            sAgg2bf[1][col] = f2bf(mxB);
        }
    }
    __syncthreads();

    // ---- aggdot: z[vox][n] = agg2 . w3s[64:128] via tiny MFMA (C rows 0/1) ----
    f32x4 zacc[2];
    #pragma unroll
    for (int nt = 0; nt < 2; ++nt) zacc[nt] = (f32x4){0.f,0.f,0.f,0.f};
    #pragma unroll
    for (int ks2 = 0; ks2 < 2; ++ks2) {
        const bf16x8 af = *(const bf16x8*)&sAgg2bf[m15 & 1][ks2*32 + g*8];
        #pragma unroll
        for (int nt = 0; nt < 2; ++nt)
            zacc[nt] = __builtin_amdgcn_mfma_f32_16x16x32_bf16(af, b3f[nt][2+ks2], zacc[nt], 0, 0, 0);
    }
    if (g == 0) {
        #pragma unroll
        for (int nt = 0; nt < 2; ++nt) {
            const int col = (w*2 + nt)*16 + m15;
            sZ[0][col] = zacc[nt][0];   // C row 0 = voxel A
            sZ[1][col] = zacc[nt][1];   // C row 1 = voxel B
        }
    }
    __syncthreads();   // sZ visible before per-pass epilogues

    // ---- layer 3 MFMA in TWO sequential passes (acc3[6] live at a time) ----
    #pragma unroll
    for (int pass = 0; pass < 2; ++pass) {
        f32x4 acc3[6];
        #pragma unroll
        for (int mt = 0; mt < 6; ++mt) acc3[mt] = (f32x4){0.f,0.f,0.f,0.f};
        #pragma unroll
        for (int mt = 0; mt < 6; ++mt) {
            const int vox = (mt >= 3);
            const int limV = vox ? limB : limA;
            if ((mt - vox*3) < limV) {
                const bf16x8 af0 = *(const bf16x8*)&sBfrag[((mt*2 + 0)*64 + lane)*8];
                const bf16x8 af1 = *(const bf16x8*)&sBfrag[((mt*2 + 1)*64 + lane)*8];
                acc3[mt] = __builtin_amdgcn_mfma_f32_16x16x32_bf16(af0, b3f[pass][0], acc3[mt], 0, 0, 0);
                acc3[mt] = __builtin_amdgcn_mfma_f32_16x16x32_bf16(af1, b3f[pass][1], acc3[mt], 0, 0, 0);
            }
        }
        // epilogue: relu(acc + bias + z) -> masked max over rows -> out
        const int col = (w*2 + pass)*16 + m15;
        const float bA = bb3[col] + sZ[0][col];
        const float bB = bb3[col] + sZ[1][col];
        float mxA = 0.f, mxB = 0.f;
        #pragma unroll
        for (int mt = 0; mt < 3; ++mt) {
            if (mt < limA) {
                #pragma unroll
                for (int r = 0; r < 4; ++r) {
                    const int tl = mt*16 + g*4 + r;
                    const float hA = fmaxf(acc3[mt][r] + bA, 0.f);
                    if (tl < nvA) mxA = fmaxf(mxA, hA);
                }
            }
            if (mt < limB) {
                #pragma unroll
                for (int r = 0; r < 4; ++r) {
                    const int tl = mt*16 + g*4 + r;
                    const float hB = fmaxf(acc3[mt+3][r] + bB, 0.f);
                    if (tl < nvB) mxB = fmaxf(mxB, hB);
                }
            }
        }
        mxA = fmaxf(mxA, __shfl_xor(mxA, 16));
        mxA = fmaxf(mxA, __shfl_xor(mxA, 32));
        mxB = fmaxf(mxB, __shfl_xor(mxB, 16));
        mxB = fmaxf(mxB, __shfl_xor(mxB, 32));
        if (g == 0) out[(size_t)kA*128 + col] = mxA;
        if (g == 1 && hasB) out[(size_t)kB*128 + col] = mxB;
    }
}

extern "C" void kernel_launch(void* const* d_in, const int* in_sizes, int n_in,
                              void* d_out, int out_size, void* d_ws, size_t ws_size,
                              hipStream_t stream) {
    const float* feat = (const float*)d_in[0];
    const int*   nvx  = (const int*)d_in[1];
    const float* w1 = (const float*)d_in[3];
    const float* b1 = (const float*)d_in[4];
    const float* g1 = (const float*)d_in[5];
    const float* be1= (const float*)d_in[6];
    const float* m1 = (const float*)d_in[7];
    const float* v1 = (const float*)d_in[8];
    const float* w2 = (const float*)d_in[9];
    const float* b2 = (const float*)d_in[10];
    const float* g2 = (const float*)d_in[11];
    const float* be2= (const float*)d_in[12];
    const float* m2 = (const float*)d_in[13];
    const float* v2 = (const float*)d_in[14];
    const float* w3 = (const float*)d_in[15];
    const float* b3 = (const float*)d_in[16];
    const float* g3 = (const float*)d_in[17];
    const float* be3= (const float*)d_in[18];
    const float* m3 = (const float*)d_in[19];
    const float* v3 = (const float*)d_in[20];
    float* out = (float*)d_out;

    const int K = in_sizes[1];

    vfe_prep<<<74, 256, 0, stream>>>(w1,b1,g1,be1,m1,v1, w2,b2,g2,be2,m2,v2,
                                     w3,b3,g3,be3,m3,v3, d_ws);
    vfe_fused<<<(K + 1) / 2, 256, 0, stream>>>(feat, nvx, d_ws, out, K);
}

// Round 8
// 79.466 us; speedup vs baseline: 12.4094x; 1.0889x over previous
//
#include <hip/hip_runtime.h>

constexpr float EPS = 1e-5f;

typedef __attribute__((ext_vector_type(8))) short bf16x8;
typedef __attribute__((ext_vector_type(4))) float f32x4;

// d_ws layout (bytes):
//   0      : w3p  - 16384 bf16 (fragment-packed, BN-scale folded)
//   32768  : w2p  -  2048 bf16 (fragment-packed, BN-scale folded)
//   37376  : bias1-  16 f32 ; 37440: bias2- 64 f32 ; 37696: bias3- 128 f32
//   38208  : w1p  -   512 bf16 (fragment-packed, zeros for k>=8)
#define W2P_OFF 32768
#define B1_OFF  37376
#define B2_OFF  37440
#define B3_OFF  37696
#define W1P_OFF 38208

__device__ __forceinline__ ushort f2bf(float x) {
    union { float f; unsigned u; } a; a.f = x;
    unsigned r = a.u + 0x7fffu + ((a.u >> 16) & 1u);   // RTNE (finite inputs only)
    return (ushort)(r >> 16);
}

// Pack weights into per-lane MFMA fragment order, BN scale folded.
// k -> slot map: k = ks*32 + g*8 + e (same bijection as A-side staging).
__global__ void vfe_prep(
    const float* __restrict__ w1, const float* __restrict__ b1,
    const float* __restrict__ g1, const float* __restrict__ be1,
    const float* __restrict__ m1, const float* __restrict__ v1,
    const float* __restrict__ w2, const float* __restrict__ b2,
    const float* __restrict__ g2, const float* __restrict__ be2,
    const float* __restrict__ m2, const float* __restrict__ v2,
    const float* __restrict__ w3, const float* __restrict__ b3,
    const float* __restrict__ g3, const float* __restrict__ be3,
    const float* __restrict__ m3, const float* __restrict__ v3,
    void* __restrict__ ws)
{
    ushort* w3p = (ushort*)ws;
    ushort* w2p = (ushort*)((char*)ws + W2P_OFF);
    ushort* w1p = (ushort*)((char*)ws + W1P_OFF);
    float*  bb1 = (float*)((char*)ws + B1_OFF);
    float*  bb2 = (float*)((char*)ws + B2_OFF);
    float*  bb3 = (float*)((char*)ws + B3_OFF);

    const int i = blockIdx.x * 256 + threadIdx.x;
    if (i < 16384) {                       // w3p: ((nt*4+ks)*64 + l)*8 + e
        const int e = i & 7, l = (i >> 3) & 63, rest = i >> 9;
        const int ks = rest & 3, nt = rest >> 2, g = l >> 4;
        const int k = ks * 32 + g * 8 + e;
        const int n = nt * 16 + (l & 15);
        const float s = g3[n] * rsqrtf(v3[n] + EPS);
        w3p[i] = f2bf(w3[k * 128 + n] * s);
    } else if (i < 18432) {                // w2p: (nt*64 + l)*8 + e
        const int j = i - 16384;
        const int e = j & 7, l = (j >> 3) & 63, nt = j >> 9, g = l >> 4;
        const int k = g * 8 + e;
        const int n = nt * 16 + (l & 15);
        const float s = g2[n] * rsqrtf(v2[n] + EPS);
        w2p[j] = f2bf(w2[k * 64 + n] * s);
    } else if (i < 18944) {                // w1p: l*8 + e, zeros for k>=8
        const int j = i - 18432;
        const int e = j & 7, l = j >> 3;
        const int klog = (l >> 4) * 8 + e;
        const int u = l & 15;
        const float s = g1[u] * rsqrtf(v1[u] + EPS);
        w1p[j] = (klog < 8) ? f2bf(w1[klog * 16 + u] * s) : (ushort)0;
    } else if (i < 19152) {
        const int j = i - 18944;
        if (j < 16) {
            const int u = j;
            bb1[u] = (b1[u] - m1[u]) * (g1[u] * rsqrtf(v1[u] + EPS)) + be1[u];
        } else if (j < 80) {
            const int u = j - 16;
            bb2[u] = (b2[u] - m2[u]) * (g2[u] * rsqrtf(v2[u] + EPS)) + be2[u];
        } else {
            const int u = j - 80;
            bb3[u] = (b3[u] - m3[u]) * (g3[u] * rsqrtf(v3[u] + EPS)) + be3[u];
        }
    }
}

// 2 voxels per block, 256 threads / 4 waves. Rows 0-47 = voxel A, 48-95 = voxel B.
__global__ __launch_bounds__(256, 4) void vfe_fused(
    const float* __restrict__ feat,
    const int* __restrict__ nvox,
    const void* __restrict__ ws,
    float* __restrict__ out,
    int K)
{
    __shared__ __align__(16) ushort sX0bf[96][8];       // x0 rows, packed bf16 (16B/row)
    __shared__ __align__(16) ushort sAfrag[6*4*16*8];   // x1, A-fragment order
    __shared__ __align__(16) ushort sBfrag[6*2*64*8];   // h2, A-fragment order
    __shared__ float  sP[6][17];                        // per-tile col-max of h1
    __shared__ __align__(16) ushort sAgg1bf[2][16];
    __shared__ __align__(16) ushort sAgg2bf[2][64];
    __shared__ float  sZ[2][128];

    const ushort* w3p = (const ushort*)ws;
    const ushort* w2p = (const ushort*)((const char*)ws + W2P_OFF);
    const ushort* w1p = (const ushort*)((const char*)ws + W1P_OFF);
    const float*  bb1 = (const float*)((const char*)ws + B1_OFF);
    const float*  bb2 = (const float*)((const char*)ws + B2_OFF);
    const float*  bb3 = (const float*)((const char*)ws + B3_OFF);

    const int tid  = threadIdx.x;
    const int lane = tid & 63;
    const int w    = tid >> 6;
    const int g    = lane >> 4;
    const int m15  = lane & 15;
    const int kA   = blockIdx.x * 2;
    const int kB   = kA + 1;
    const bool hasB = (kB < K);
    int nvA = nvox[kA];
    nvA = __builtin_amdgcn_readfirstlane(nvA);
    int nvB = hasB ? nvox[kB] : 1;
    nvB = __builtin_amdgcn_readfirstlane(nvB);
    const int limA = (nvA + 15) >> 4;      // 1..3, block-uniform (nv in [1,47])
    const int limB = (nvB + 15) >> 4;

    union U8 { bf16x8 v; unsigned u[4]; };

    // ---- B-fragment preloads (L2-hot, overlap with stages below) ----
    const bf16x8 b1f = *(const bf16x8*)(w1p + (size_t)lane*8);
    const bf16x8 b2f = *(const bf16x8*)(w2p + (size_t)(w*64 + lane)*8);
    bf16x8 b3f[2][4];
    #pragma unroll
    for (int nt = 0; nt < 2; ++nt)
        #pragma unroll
        for (int ks = 0; ks < 4; ++ks)
            b3f[nt][ks] = *(const bf16x8*)(w3p + (size_t)(((w*2+nt)*4+ks)*64 + lane)*8);

    // ---- stage 0: wave 0 -> voxel A, wave 1 -> voxel B; packed bf16 rows ----
    if (w < 2) {
        const int vox = w;
        const int nv  = vox ? nvB : nvA;
        const int kk  = vox ? kB : kA;
        float4 f = make_float4(0.f, 0.f, 0.f, 0.f);
        if (lane < 48 && (vox == 0 || hasB))
            f = *reinterpret_cast<const float4*>(feat + ((size_t)kk*48 + lane)*4);
        float sx = f.x, sy = f.y, sz = f.z;
        #pragma unroll
        for (int d = 1; d < 64; d <<= 1) {
            sx += __shfl_xor(sx, d);
            sy += __shfl_xor(sy, d);
            sz += __shfl_xor(sz, d);
        }
        const float inv = 1.f / (float)nv;
        if (lane < 48) {
            const float msk = (lane < nv) ? 1.f : 0.f;
            const float dd = sqrtf(f.x*f.x + f.y*f.y + f.z*f.z);
            U8 a;
            a.u[0] = (unsigned)f2bf(f.x*msk) | ((unsigned)f2bf(f.y*msk) << 16);
            a.u[1] = (unsigned)f2bf(f.z*msk) | ((unsigned)f2bf(f.w*msk) << 16);
            a.u[2] = (unsigned)f2bf((f.x - sx*inv)*msk) | ((unsigned)f2bf((f.y - sy*inv)*msk) << 16);
            a.u[3] = (unsigned)f2bf((f.z - sz*inv)*msk) | ((unsigned)f2bf(dd*msk) << 16);
            *reinterpret_cast<bf16x8*>(&sX0bf[vox*48 + lane][0]) = a.v;
        }
    }
    __syncthreads();

    // ---- layer 1 via MFMA: wave w -> tiles {w, w+4 (waves 0,1 only)} ----
    #pragma unroll
    for (int slot = 0; slot < 2; ++slot) {
        if (slot == 0 || w < 2) {
            const int tt  = (slot == 0) ? w : (w + 4);
            const int vox = (tt >= 3) ? 1 : 0;
            const int mtl = tt - vox*3;
            const int limV = vox ? limB : limA;
            const int nv   = vox ? nvB : nvA;
            if (mtl < limV) {
                const bf16x8 af = *(const bf16x8*)&sX0bf[tt*16 + m15][0];
                f32x4 zz = {0.f,0.f,0.f,0.f};
                f32x4 acc = __builtin_amdgcn_mfma_f32_16x16x32_bf16(af, b1f, zz, 0, 0, 0);
                const float bia = bb1[m15];
                float pmax = 0.f;
                #pragma unroll
                for (int r = 0; r < 4; ++r) {
                    const float h = fmaxf(acc[r] + bia, 0.f);  // zero rows -> relu(bb1): valid for agg
                    pmax = fmaxf(pmax, h);
                    const int rl = mtl*16 + g*4 + r;
                    sAfrag[((tt*4 + (m15 >> 3))*16 + (g*4 + r))*8 + (m15 & 7)] = f2bf(rl < nv ? h : 0.f);
                }
                pmax = fmaxf(pmax, __shfl_xor(pmax, 16));
                pmax = fmaxf(pmax, __shfl_xor(pmax, 32));
                if (lane < 16) sP[tt][m15] = pmax;
            }
        }
    }
    __syncthreads();
    // combine per-tile col-maxes -> agg1 (bf16)
    if (tid < 32) {
        const int u = tid & 15, vox = tid >> 4;
        const int limV = vox ? limB : limA;
        float mx = fmaxf(bb1[u], 0.f);     // analytic masked-row term (nv<48 always)
        #pragma unroll
        for (int tb = 0; tb < 3; ++tb)
            if (tb < limV) mx = fmaxf(mx, sP[vox*3 + tb][u]);
        sAgg1bf[vox][u] = f2bf(mx);
    }
    __syncthreads();
    // agg half of x1 (cols 16-31): one 16B masked write per half-row
    if (tid < 192) {
        const int t = tid >> 1, half = tid & 1;
        const int vox = (t >= 48) ? 1 : 0;
        const int tl  = t - vox*48;
        const int limV = vox ? limB : limA;
        const int nv   = vox ? nvB : nvA;
        if (tl < limV*16) {
            U8 a;
            a.v = *(const bf16x8*)&sAgg1bf[vox][half*8];
            const unsigned mm = (tl < nv) ? 0xFFFFFFFFu : 0u;
            a.u[0] &= mm; a.u[1] &= mm; a.u[2] &= mm; a.u[3] &= mm;
            *reinterpret_cast<bf16x8*>(&sAfrag[(((t >> 4)*4 + 2 + half)*16 + (t & 15))*8]) = a.v;
        }
    }
    __syncthreads();

    // ---- layer 2 MFMA: (96x32)@(32x64); wave w owns cols [16w,16w+16) ----
    f32x4 acc2[6];
    #pragma unroll
    for (int mt = 0; mt < 6; ++mt) acc2[mt] = (f32x4){0.f,0.f,0.f,0.f};
    #pragma unroll
    for (int mt = 0; mt < 6; ++mt) {
        const int vox = (mt >= 3);
        const int limV = vox ? limB : limA;
        if ((mt - vox*3) < limV) {
            const bf16x8 af = *(const bf16x8*)&sAfrag[((mt*4 + g)*16 + m15)*8];
            acc2[mt] = __builtin_amdgcn_mfma_f32_16x16x32_bf16(af, b2f, acc2[mt], 0, 0, 0);
        }
    }
    {
        const int col = w*16 + m15;
        const float bia = bb2[col];
        const int ks = col >> 5, gp = (col >> 3) & 3, e = col & 7;
        float mxA = fmaxf(bia, 0.f);       // analytic masked-row term
        float mxB = fmaxf(bia, 0.f);
        #pragma unroll
        for (int mt = 0; mt < 6; ++mt) {
            const int vox = (mt >= 3);
            const int nv   = vox ? nvB : nvA;
            const int limV = vox ? limB : limA;
            const int mtl = mt - vox*3;
            if (mtl < limV) {
                const int tb = mtl*16 + g*4;
                #pragma unroll
                for (int r = 0; r < 4; ++r) {
                    const float h = fmaxf(acc2[mt][r] + bia, 0.f);
                    if (vox) mxB = fmaxf(mxB, h); else mxA = fmaxf(mxA, h);
                    sBfrag[((mt*2 + ks)*64 + gp*16 + (g*4 + r))*8 + e] = f2bf((tb + r) < nv ? h : 0.f);
                }
            }
        }
        mxA = fmaxf(mxA, __shfl_xor(mxA, 16));
        mxA = fmaxf(mxA, __shfl_xor(mxA, 32));
        mxB = fmaxf(mxB, __shfl_xor(mxB, 16));
        mxB = fmaxf(mxB, __shfl_xor(mxB, 32));
        if (g == 0) {
            sAgg2bf[0][col] = f2bf(mxA);
            sAgg2bf[1][col] = f2bf(mxB);
        }
    }
    __syncthreads();

    // ---- aggdot: z[vox][n] = agg2 . w3s[64:128] via tiny MFMA (C rows 0/1) ----
    f32x4 zacc[2];
    #pragma unroll
    for (int nt = 0; nt < 2; ++nt) zacc[nt] = (f32x4){0.f,0.f,0.f,0.f};
    #pragma unroll
    for (int ks2 = 0; ks2 < 2; ++ks2) {
        const bf16x8 af = *(const bf16x8*)&sAgg2bf[m15 & 1][ks2*32 + g*8];
        #pragma unroll
        for (int nt = 0; nt < 2; ++nt)
            zacc[nt] = __builtin_amdgcn_mfma_f32_16x16x32_bf16(af, b3f[nt][2+ks2], zacc[nt], 0, 0, 0);
    }
    if (g == 0) {
        #pragma unroll
        for (int nt = 0; nt < 2; ++nt) {
            const int col = (w*2 + nt)*16 + m15;
            sZ[0][col] = zacc[nt][0];   // C row 0 = voxel A
            sZ[1][col] = zacc[nt][1];   // C row 1 = voxel B
        }
    }
    __syncthreads();   // sZ visible before per-pass epilogues

    // ---- layer 3 MFMA in TWO sequential passes (acc3[6] live at a time) ----
    #pragma unroll
    for (int pass = 0; pass < 2; ++pass) {
        f32x4 acc3[6];
        #pragma unroll
        for (int mt = 0; mt < 6; ++mt) acc3[mt] = (f32x4){0.f,0.f,0.f,0.f};
        #pragma unroll
        for (int mt = 0; mt < 6; ++mt) {
            const int vox = (mt >= 3);
            const int limV = vox ? limB : limA;
            if ((mt - vox*3) < limV) {
                const bf16x8 af0 = *(const bf16x8*)&sBfrag[((mt*2 + 0)*64 + lane)*8];
                const bf16x8 af1 = *(const bf16x8*)&sBfrag[((mt*2 + 1)*64 + lane)*8];
                acc3[mt] = __builtin_amdgcn_mfma_f32_16x16x32_bf16(af0, b3f[pass][0], acc3[mt], 0, 0, 0);
                acc3[mt] = __builtin_amdgcn_mfma_f32_16x16x32_bf16(af1, b3f[pass][1], acc3[mt], 0, 0, 0);
            }
        }
        // epilogue: relu(acc + bias + z) -> masked max over rows -> out
        const int col = (w*2 + pass)*16 + m15;
        const float bA = bb3[col] + sZ[0][col];
        const float bB = bb3[col] + sZ[1][col];
        float mxA = 0.f, mxB = 0.f;
        #pragma unroll
        for (int mt = 0; mt < 3; ++mt) {
            if (mt < limA) {
                #pragma unroll
                for (int r = 0; r < 4; ++r) {
                    const int tl = mt*16 + g*4 + r;
                    const float hA = fmaxf(acc3[mt][r] + bA, 0.f);
                    if (tl < nvA) mxA = fmaxf(mxA, hA);
                }
            }
            if (mt < limB) {
                #pragma unroll
                for (int r = 0; r < 4; ++r) {
                    const int tl = mt*16 + g*4 + r;
                    const float hB = fmaxf(acc3[mt+3][r] + bB, 0.f);
                    if (tl < nvB) mxB = fmaxf(mxB, hB);
                }
            }
        }
        mxA = fmaxf(mxA, __shfl_xor(mxA, 16));
        mxA = fmaxf(mxA, __shfl_xor(mxA, 32));
        mxB = fmaxf(mxB, __shfl_xor(mxB, 16));
        mxB = fmaxf(mxB, __shfl_xor(mxB, 32));
        if (g == 0) out[(size_t)kA*128 + col] = mxA;
        if (g == 1 && hasB) out[(size_t)kB*128 + col] = mxB;
    }
}

extern "C" void kernel_launch(void* const* d_in, const int* in_sizes, int n_in,
                              void* d_out, int out_size, void* d_ws, size_t ws_size,
                              hipStream_t stream) {
    const float* feat = (const float*)d_in[0];
    const int*   nvx  = (const int*)d_in[1];
    const float* w1 = (const float*)d_in[3];
    const float* b1 = (const float*)d_in[4];
    const float* g1 = (const float*)d_in[5];
    const float* be1= (const float*)d_in[6];
    const float* m1 = (const float*)d_in[7];
    const float* v1 = (const float*)d_in[8];
    const float* w2 = (const float*)d_in[9];
    const float* b2 = (const float*)d_in[10];
    const float* g2 = (const float*)d_in[11];
    const float* be2= (const float*)d_in[12];
    const float* m2 = (const float*)d_in[13];
    const float* v2 = (const float*)d_in[14];
    const float* w3 = (const float*)d_in[15];
    const float* b3 = (const float*)d_in[16];
    const float* g3 = (const float*)d_in[17];
    const float* be3= (const float*)d_in[18];
    const float* m3 = (const float*)d_in[19];
    const float* v3 = (const float*)d_in[20];
    float* out = (float*)d_out;

    const int K = in_sizes[1];

    vfe_prep<<<75, 256, 0, stream>>>(w1,b1,g1,be1,m1,v1, w2,b2,g2,be2,m2,v2,
                                     w3,b3,g3,be3,m3,v3, d_ws);
    vfe_fused<<<(K + 1) / 2, 256, 0, stream>>>(feat, nvx, d_ws, out, K);
}

// Round 9
// 75.413 us; speedup vs baseline: 13.0762x; 1.0537x over previous
//
#include <hip/hip_runtime.h>

constexpr float EPS = 1e-5f;

typedef __attribute__((ext_vector_type(8))) short bf16x8;
typedef __attribute__((ext_vector_type(4))) float f32x4;

// d_ws layout (bytes):
//   0      : w3p[8nt][4ks][64][8]  bf16, BN-folded. ks 0,1 = h2 rows (k<64); ks 2,3 = agg rows (k>=64)
//   32768  : w2p[2sel][4nt][64][8] bf16, BN-folded. sel0 = w2 rows 0-15 (h1), sel1 = rows 16-31 (agg); k-slots>=16 are ZERO
//   40960  : w1p[64][8]            bf16, BN-folded, zeros for k>=8
//   41984  : bb1 f32[16] ; 42048: bb2 f32[64] ; 42304: bb3 f32[128]
#define W2P_OFF 32768
#define W1P_OFF 40960
#define B1_OFF  41984
#define B2_OFF  42048
#define B3_OFF  42304

__device__ __forceinline__ ushort f2bf(float x) {
    union { float f; unsigned u; } a; a.f = x;
    unsigned r = a.u + 0x7fffu + ((a.u >> 16) & 1u);   // RTNE (finite inputs only)
    return (ushort)(r >> 16);
}

__device__ __forceinline__ unsigned cvtpk(float lo, float hi) {
    unsigned r;
    asm("v_cvt_pk_bf16_f32 %0, %1, %2" : "=v"(r) : "v"(lo), "v"(hi));
    return r;
}

__global__ void vfe_prep(
    const float* __restrict__ w1, const float* __restrict__ b1,
    const float* __restrict__ g1, const float* __restrict__ be1,
    const float* __restrict__ m1, const float* __restrict__ v1,
    const float* __restrict__ w2, const float* __restrict__ b2,
    const float* __restrict__ g2, const float* __restrict__ be2,
    const float* __restrict__ m2, const float* __restrict__ v2,
    const float* __restrict__ w3, const float* __restrict__ b3,
    const float* __restrict__ g3, const float* __restrict__ be3,
    const float* __restrict__ m3, const float* __restrict__ v3,
    void* __restrict__ ws)
{
    ushort* w3p = (ushort*)ws;
    ushort* w2p = (ushort*)((char*)ws + W2P_OFF);
    ushort* w1p = (ushort*)((char*)ws + W1P_OFF);
    float*  bb1 = (float*)((char*)ws + B1_OFF);
    float*  bb2 = (float*)((char*)ws + B2_OFF);
    float*  bb3 = (float*)((char*)ws + B3_OFF);

    const int i = blockIdx.x * 256 + threadIdx.x;
    if (i < 16384) {                       // w3p: ((nt*4+ks)*64 + l)*8 + e
        const int e = i & 7, l = (i >> 3) & 63, rest = i >> 9;
        const int ks = rest & 3, nt = rest >> 2, g = l >> 4;
        const int k = ks * 32 + g * 8 + e;
        const int n = nt * 16 + (l & 15);
        const float s = g3[n] * rsqrtf(v3[n] + EPS);
        w3p[i] = f2bf(w3[k * 128 + n] * s);
    } else if (i < 20480) {                // w2p: ((sel*4+nt)*64 + l)*8 + e ; zeros k>=16
        const int j = i - 16384;
        const int e = j & 7, l = (j >> 3) & 63, rest = j >> 9;
        const int nt = rest & 3, sel = rest >> 2;
        const int klog = (l >> 4) * 8 + e;             // 0..31, real only <16
        const int n = nt * 16 + (l & 15);
        const float s = g2[n] * rsqrtf(v2[n] + EPS);
        w2p[j] = (klog < 16) ? f2bf(w2[(sel * 16 + klog) * 64 + n] * s) : (ushort)0;
    } else if (i < 20992) {                // w1p: l*8 + e, zeros for k>=8
        const int j = i - 20480;
        const int e = j & 7, l = j >> 3;
        const int klog = (l >> 4) * 8 + e;
        const int u = l & 15;
        const float s = g1[u] * rsqrtf(v1[u] + EPS);
        w1p[j] = (klog < 8) ? f2bf(w1[klog * 16 + u] * s) : (ushort)0;
    } else if (i < 21200) {
        const int j = i - 20992;
        if (j < 16) {
            const int u = j;
            bb1[u] = (b1[u] - m1[u]) * (g1[u] * rsqrtf(v1[u] + EPS)) + be1[u];
        } else if (j < 80) {
            const int u = j - 16;
            bb2[u] = (b2[u] - m2[u]) * (g2[u] * rsqrtf(v2[u] + EPS)) + be2[u];
        } else {
            const int u = j - 80;
            bb3[u] = (b3[u] - m3[u]) * (g3[u] * rsqrtf(v3[u] + EPS)) + be3[u];
        }
    }
}

// 2 voxels per block, 256 threads / 4 waves. Tiles 0-2 = voxel A, 3-5 = voxel B.
__global__ __launch_bounds__(256, 4) void vfe_fused(
    const float* __restrict__ feat,
    const int* __restrict__ nvox,
    const void* __restrict__ ws,
    float* __restrict__ out,
    int K)
{
    __shared__ __align__(16) ushort sX0bf[96][8];       // x0 rows, bf16, masked (16B/row)
    __shared__ __align__(16) ushort sAfrag[6 * 16 * 24];// h1: [tile][row16][chan pad24]
    __shared__ __align__(16) ushort sBfrag[6 * 2 * 64 * 8]; // h2, fragment order (R8 layout)
    __shared__ float  sP[6][17];                        // per-tile col-max of h1
    __shared__ __align__(16) ushort sAgg1bf[2][16];
    __shared__ __align__(16) ushort sAgg2bf[2][64];

    const ushort* w3p = (const ushort*)ws;
    const ushort* w2p = (const ushort*)((const char*)ws + W2P_OFF);
    const ushort* w1p = (const ushort*)((const char*)ws + W1P_OFF);
    const float*  bb1 = (const float*)((const char*)ws + B1_OFF);
    const float*  bb2 = (const float*)((const char*)ws + B2_OFF);
    const float*  bb3 = (const float*)((const char*)ws + B3_OFF);

    const int tid  = threadIdx.x;
    const int lane = tid & 63;
    const int w    = tid >> 6;
    const int g    = lane >> 4;
    const int m15  = lane & 15;
    const int kA   = blockIdx.x * 2;
    const int kB   = kA + 1;
    const bool hasB = (kB < K);
    int nvA = nvox[kA];
    nvA = __builtin_amdgcn_readfirstlane(nvA);
    int nvB = hasB ? nvox[kB] : 1;
    nvB = __builtin_amdgcn_readfirstlane(nvB);
    const int limA  = (nvA + 15) >> 4;     // tiles touched (1..3)
    const int limB  = (nvB + 15) >> 4;
    const int fullA = nvA >> 4;            // fully-live tiles (0..2)
    const int fullB = nvB >> 4;

    union U8 { bf16x8 v; unsigned u[4]; };

    // ---- B-fragment preloads (L2-hot) ----
    const bf16x8 b1f   = *(const bf16x8*)(w1p + (size_t)lane * 8);
    const bf16x8 w2lof = *(const bf16x8*)(w2p + (size_t)((0 * 4 + w) * 64 + lane) * 8);
    const bf16x8 w2hif = *(const bf16x8*)(w2p + (size_t)((1 * 4 + w) * 64 + lane) * 8);
    bf16x8 b3f[2][4];
    #pragma unroll
    for (int nt = 0; nt < 2; ++nt)
        #pragma unroll
        for (int ks = 0; ks < 4; ++ks)
            b3f[nt][ks] = *(const bf16x8*)(w3p + (size_t)(((w * 2 + nt) * 4 + ks) * 64 + lane) * 8);

    // ---- stage 0: wave 0 -> voxel A, wave 1 -> voxel B ----
    if (w < 2) {
        const int vox = w;
        const int nv  = vox ? nvB : nvA;
        const int kk  = vox ? kB : kA;
        float4 f = make_float4(0.f, 0.f, 0.f, 0.f);
        if (lane < 48 && (vox == 0 || hasB))
            f = *reinterpret_cast<const float4*>(feat + ((size_t)kk * 48 + lane) * 4);
        float sx = f.x, sy = f.y, sz = f.z;
        #pragma unroll
        for (int d = 1; d < 64; d <<= 1) {
            sx += __shfl_xor(sx, d);
            sy += __shfl_xor(sy, d);
            sz += __shfl_xor(sz, d);
        }
        const float inv = 1.f / (float)nv;
        if (lane < 48) {
            const float msk = (lane < nv) ? 1.f : 0.f;
            const float dd = sqrtf(f.x * f.x + f.y * f.y + f.z * f.z);
            U8 a;
            a.u[0] = cvtpk(f.x * msk, f.y * msk);
            a.u[1] = cvtpk(f.z * msk, f.w * msk);
            a.u[2] = cvtpk((f.x - sx * inv) * msk, (f.y - sy * inv) * msk);
            a.u[3] = cvtpk((f.z - sz * inv) * msk, dd * msk);
            *reinterpret_cast<bf16x8*>(&sX0bf[vox * 48 + lane][0]) = a.v;
        }
    }
    __syncthreads();

    // ---- layer 1 MFMA (C-init = bias): wave w -> tiles {w, w+4 (waves 0,1)} ----
    {
        const float bia = bb1[m15];
        #pragma unroll
        for (int slot = 0; slot < 2; ++slot) {
            if (slot == 0 || w < 2) {
                const int tt  = (slot == 0) ? w : (w + 4);
                const int vox = (tt >= 3) ? 1 : 0;
                const int mtl = tt - vox * 3;
                const int limV = vox ? limB : limA;
                if (mtl < limV) {
                    const bf16x8 af = *(const bf16x8*)&sX0bf[tt * 16 + m15][0];
                    f32x4 ci = {bia, bia, bia, bia};
                    f32x4 acc = __builtin_amdgcn_mfma_f32_16x16x32_bf16(af, b1f, ci, 0, 0, 0);
                    float pmax = 0.f;
                    #pragma unroll
                    for (int r = 0; r < 4; ++r) {
                        const float h = fmaxf(acc[r], 0.f);   // rows>=nv -> relu(bb1): the analytic agg term
                        pmax = fmaxf(pmax, h);
                        sAfrag[(tt * 16 + g * 4 + r) * 24 + m15] = f2bf(h);  // unmasked
                    }
                    pmax = fmaxf(pmax, __shfl_xor(pmax, 16));
                    pmax = fmaxf(pmax, __shfl_xor(pmax, 32));
                    if (lane < 16) sP[tt][m15] = pmax;
                }
            }
        }
    }
    __syncthreads();
    // ---- agg1 combine (32 threads) -> sAgg1bf ----
    if (tid < 32) {
        const int u = tid & 15, vox = tid >> 4;
        const int limV = vox ? limB : limA;
        float mx = fmaxf(bb1[u], 0.f);     // analytic masked-row term (nv<48 always)
        #pragma unroll
        for (int tb = 0; tb < 3; ++tb)
            if (tb < limV) mx = fmaxf(mx, sP[vox * 3 + tb][u]);
        sAgg1bf[vox][u] = f2bf(mx);
    }
    __syncthreads();

    // ---- z2-fold MFMA: A rows alternate voxA/voxB -> C reg r holds init for vox (r&1) ----
    const int col2 = w * 16 + m15;
    const float bb2c = bb2[col2];
    f32x4 z2acc;
    {
        const bf16x8 az2 = *(const bf16x8*)&sAgg1bf[m15 & 1][(g & 1) * 8];  // k>=16 slots replicate (x w2p zeros)
        f32x4 ci = {bb2c, bb2c, bb2c, bb2c};
        z2acc = __builtin_amdgcn_mfma_f32_16x16x32_bf16(az2, w2hif, ci, 0, 0, 0);
    }
    const float iA2 = z2acc[0];   // bb2 + z2 (voxel A)
    const float iB2 = z2acc[1];   // bb2 + z2 (voxel B)

    // ---- layer 2 MFMA (C-init = bb2+z2): 6 tiles, K=16 real (A k>=16 replicated, B zero) ----
    f32x4 acc2[6];
    #pragma unroll
    for (int mt = 0; mt < 6; ++mt) {
        const int vox = (mt >= 3);
        const int limV = vox ? limB : limA;
        if ((mt - vox * 3) < limV) {
            const bf16x8 af = *(const bf16x8*)&sAfrag[(mt * 16 + m15) * 24 + (g & 1) * 8];
            const float ci = vox ? iB2 : iA2;
            f32x4 c = {ci, ci, ci, ci};
            acc2[mt] = __builtin_amdgcn_mfma_f32_16x16x32_bf16(af, w2lof, c, 0, 0, 0);
        }
    }
    // epilogue L2: h2 = relu(acc2); stage unmasked; agg2 with full/boundary split
    {
        const int ks = col2 >> 5, gp = (col2 >> 3) & 3, e = col2 & 7;
        float mxA = fmaxf(bb2c, 0.f);      // analytic masked-row term (NO z2 for masked rows)
        float mxB = fmaxf(bb2c, 0.f);
        #pragma unroll
        for (int mt = 0; mt < 6; ++mt) {
            const int vox = (mt >= 3);
            const int nv    = vox ? nvB : nvA;
            const int limV  = vox ? limB : limA;
            const int fullV = vox ? fullB : fullA;
            const int mtl = mt - vox * 3;
            if (mtl < limV) {
                float h[4];
                #pragma unroll
                for (int r = 0; r < 4; ++r) {
                    h[r] = fmaxf(acc2[mt][r], 0.f);
                    sBfrag[((mt * 2 + ks) * 64 + gp * 16 + (g * 4 + r)) * 8 + e] = f2bf(h[r]);
                }
                if (mtl < fullV) {          // fully-live tile: unconditional
                    float t01 = fmaxf(h[0], h[1]), t23 = fmaxf(h[2], h[3]);
                    if (vox) mxB = fmaxf(mxB, fmaxf(t01, t23));
                    else     mxA = fmaxf(mxA, fmaxf(t01, t23));
                } else {                     // boundary tile: per-row predicate
                    #pragma unroll
                    for (int r = 0; r < 4; ++r) {
                        if (mtl * 16 + g * 4 + r < nv) {
                            if (vox) mxB = fmaxf(mxB, h[r]);
                            else     mxA = fmaxf(mxA, h[r]);
                        }
                    }
                }
            }
        }
        mxA = fmaxf(mxA, __shfl_xor(mxA, 16));
        mxA = fmaxf(mxA, __shfl_xor(mxA, 32));
        mxB = fmaxf(mxB, __shfl_xor(mxB, 16));
        mxB = fmaxf(mxB, __shfl_xor(mxB, 32));
        if (g == 0) {
            sAgg2bf[0][col2] = f2bf(mxA);
            sAgg2bf[1][col2] = f2bf(mxB);
        }
    }
    __syncthreads();

    // ---- aggdot z3 (C-init = bb3; A rows alternate vox) -> reg0/reg1 = L3 init A/B ----
    float iA3[2], iB3[2];
    #pragma unroll
    for (int nt = 0; nt < 2; ++nt) {
        const float bb3c = bb3[(w * 2 + nt) * 16 + m15];
        f32x4 z = {bb3c, bb3c, bb3c, bb3c};
        #pragma unroll
        for (int ks2 = 0; ks2 < 2; ++ks2) {
            const bf16x8 af = *(const bf16x8*)&sAgg2bf[m15 & 1][ks2 * 32 + g * 8];
            z = __builtin_amdgcn_mfma_f32_16x16x32_bf16(af, b3f[nt][2 + ks2], z, 0, 0, 0);
        }
        iA3[nt] = z[0];
        iB3[nt] = z[1];
    }

    // ---- layer 3 MFMA in two passes (C-init = bb3 + z3) ----
    #pragma unroll
    for (int pass = 0; pass < 2; ++pass) {
        f32x4 acc3[6];
        #pragma unroll
        for (int mt = 0; mt < 6; ++mt) {
            const int vox = (mt >= 3);
            const int limV = vox ? limB : limA;
            if ((mt - vox * 3) < limV) {
                const bf16x8 af0 = *(const bf16x8*)&sBfrag[((mt * 2 + 0) * 64 + lane) * 8];
                const bf16x8 af1 = *(const bf16x8*)&sBfrag[((mt * 2 + 1) * 64 + lane) * 8];
                const float ci = vox ? iB3[pass] : iA3[pass];
                f32x4 c = {ci, ci, ci, ci};
                acc3[mt] = __builtin_amdgcn_mfma_f32_16x16x32_bf16(af0, b3f[pass][0], c, 0, 0, 0);
                acc3[mt] = __builtin_amdgcn_mfma_f32_16x16x32_bf16(af1, b3f[pass][1], acc3[mt], 0, 0, 0);
            }
        }
        // epilogue: mx = max over rows<nv of relu(acc3) (relu folded into fmax, mx>=0)
        const int col = (w * 2 + pass) * 16 + m15;
        float mxA = 0.f, mxB = 0.f;
        #pragma unroll
        for (int mt = 0; mt < 3; ++mt) {
            if (mt < fullA) {
                float t01 = fmaxf(acc3[mt][0], acc3[mt][1]);
                float t23 = fmaxf(acc3[mt][2], acc3[mt][3]);
                mxA = fmaxf(mxA, fmaxf(t01, t23));
            } else if (mt < limA) {
                #pragma unroll
                for (int r = 0; r < 4; ++r)
                    if (mt * 16 + g * 4 + r < nvA) mxA = fmaxf(mxA, acc3[mt][r]);
            }
            if (mt < fullB) {
                float t01 = fmaxf(acc3[mt + 3][0], acc3[mt + 3][1]);
                float t23 = fmaxf(acc3[mt + 3][2], acc3[mt + 3][3]);
                mxB = fmaxf(mxB, fmaxf(t01, t23));
            } else if (mt < limB) {
                #pragma unroll
                for (int r = 0; r < 4; ++r)
                    if (mt * 16 + g * 4 + r < nvB) mxB = fmaxf(mxB, acc3[mt + 3][r]);
            }
        }
        mxA = fmaxf(mxA, __shfl_xor(mxA, 16));
        mxA = fmaxf(mxA, __shfl_xor(mxA, 32));
        mxB = fmaxf(mxB, __shfl_xor(mxB, 16));
        mxB = fmaxf(mxB, __shfl_xor(mxB, 32));
        if (g == 0) out[(size_t)kA * 128 + col] = mxA;
        if (g == 1 && hasB) out[(size_t)kB * 128 + col] = mxB;
    }
}

extern "C" void kernel_launch(void* const* d_in, const int* in_sizes, int n_in,
                              void* d_out, int out_size, void* d_ws, size_t ws_size,
                              hipStream_t stream) {
    const float* feat = (const float*)d_in[0];
    const int*   nvx  = (const int*)d_in[1];
    const float* w1 = (const float*)d_in[3];
    const float* b1 = (const float*)d_in[4];
    const float* g1 = (const float*)d_in[5];
    const float* be1= (const float*)d_in[6];
    const float* m1 = (const float*)d_in[7];
    const float* v1 = (const float*)d_in[8];
    const float* w2 = (const float*)d_in[9];
    const float* b2 = (const float*)d_in[10];
    const float* g2 = (const float*)d_in[11];
    const float* be2= (const float*)d_in[12];
    const float* m2 = (const float*)d_in[13];
    const float* v2 = (const float*)d_in[14];
    const float* w3 = (const float*)d_in[15];
    const float* b3 = (const float*)d_in[16];
    const float* g3 = (const float*)d_in[17];
    const float* be3= (const float*)d_in[18];
    const float* m3 = (const float*)d_in[19];
    const float* v3 = (const float*)d_in[20];
    float* out = (float*)d_out;

    const int K = in_sizes[1];

    vfe_prep<<<84, 256, 0, stream>>>(w1,b1,g1,be1,m1,v1, w2,b2,g2,be2,m2,v2,
                                     w3,b3,g3,be3,m3,v3, d_ws);
    vfe_fused<<<(K + 1) / 2, 256, 0, stream>>>(feat, nvx, d_ws, out, K);
}

// Round 10
// 73.970 us; speedup vs baseline: 13.3314x; 1.0195x over previous
//
#include <hip/hip_runtime.h>

constexpr float EPS = 1e-5f;

typedef __attribute__((ext_vector_type(8))) short bf16x8;
typedef __attribute__((ext_vector_type(4))) float f32x4;

// d_ws layout (bytes):
//   0      : w3p[8nt][4ks][64][8]  bf16, BN-folded. ks 0,1 = h2 rows (k<64); ks 2,3 = agg rows (k>=64)
//   32768  : w2p[2sel][4nt][64][8] bf16, BN-folded. sel0 = w2 rows 0-15 (h1), sel1 = rows 16-31 (agg); k-slots>=16 ZERO
//   40960  : w1p[64][8]            bf16, BN-folded, zeros for k>=8
//   41984  : bb1 f32[16] ; 42048: bb2 f32[64] ; 42304: bb3 f32[128]
#define W2P_OFF 32768
#define W1P_OFF 40960
#define B1_OFF  41984
#define B2_OFF  42048
#define B3_OFF  42304

__device__ __forceinline__ ushort f2bf(float x) {
    union { float f; unsigned u; } a; a.f = x;
    unsigned r = a.u + 0x7fffu + ((a.u >> 16) & 1u);   // RTNE (finite inputs only)
    return (ushort)(r >> 16);
}

__device__ __forceinline__ unsigned cvtpk(float lo, float hi) {
    unsigned r;
    asm("v_cvt_pk_bf16_f32 %0, %1, %2" : "=v"(r) : "v"(lo), "v"(hi));
    return r;
}

__global__ void vfe_prep(
    const float* __restrict__ w1, const float* __restrict__ b1,
    const float* __restrict__ g1, const float* __restrict__ be1,
    const float* __restrict__ m1, const float* __restrict__ v1,
    const float* __restrict__ w2, const float* __restrict__ b2,
    const float* __restrict__ g2, const float* __restrict__ be2,
    const float* __restrict__ m2, const float* __restrict__ v2,
    const float* __restrict__ w3, const float* __restrict__ b3,
    const float* __restrict__ g3, const float* __restrict__ be3,
    const float* __restrict__ m3, const float* __restrict__ v3,
    void* __restrict__ ws)
{
    ushort* w3p = (ushort*)ws;
    ushort* w2p = (ushort*)((char*)ws + W2P_OFF);
    ushort* w1p = (ushort*)((char*)ws + W1P_OFF);
    float*  bb1 = (float*)((char*)ws + B1_OFF);
    float*  bb2 = (float*)((char*)ws + B2_OFF);
    float*  bb3 = (float*)((char*)ws + B3_OFF);

    const int i = blockIdx.x * 256 + threadIdx.x;
    if (i < 16384) {                       // w3p: ((nt*4+ks)*64 + l)*8 + e
        const int e = i & 7, l = (i >> 3) & 63, rest = i >> 9;
        const int ks = rest & 3, nt = rest >> 2, g = l >> 4;
        const int k = ks * 32 + g * 8 + e;
        const int n = nt * 16 + (l & 15);
        const float s = g3[n] * rsqrtf(v3[n] + EPS);
        w3p[i] = f2bf(w3[k * 128 + n] * s);
    } else if (i < 20480) {                // w2p: ((sel*4+nt)*64 + l)*8 + e ; zeros k>=16
        const int j = i - 16384;
        const int e = j & 7, l = (j >> 3) & 63, rest = j >> 9;
        const int nt = rest & 3, sel = rest >> 2;
        const int klog = (l >> 4) * 8 + e;             // 0..31, real only <16
        const int n = nt * 16 + (l & 15);
        const float s = g2[n] * rsqrtf(v2[n] + EPS);
        w2p[j] = (klog < 16) ? f2bf(w2[(sel * 16 + klog) * 64 + n] * s) : (ushort)0;
    } else if (i < 20992) {                // w1p: l*8 + e, zeros for k>=8
        const int j = i - 20480;
        const int e = j & 7, l = j >> 3;
        const int klog = (l >> 4) * 8 + e;
        const int u = l & 15;
        const float s = g1[u] * rsqrtf(v1[u] + EPS);
        w1p[j] = (klog < 8) ? f2bf(w1[klog * 16 + u] * s) : (ushort)0;
    } else if (i < 21200) {
        const int j = i - 20992;
        if (j < 16) {
            const int u = j;
            bb1[u] = (b1[u] - m1[u]) * (g1[u] * rsqrtf(v1[u] + EPS)) + be1[u];
        } else if (j < 80) {
            const int u = j - 16;
            bb2[u] = (b2[u] - m2[u]) * (g2[u] * rsqrtf(v2[u] + EPS)) + be2[u];
        } else {
            const int u = j - 80;
            bb3[u] = (b3[u] - m3[u]) * (g3[u] * rsqrtf(v3[u] + EPS)) + be3[u];
        }
    }
}

#define NV(v)   ((v)==0?nv0:(v)==1?nv1:(v)==2?nv2:nv3)
#define LIM(v)  ((v)==0?lim0:(v)==1?lim1:(v)==2?lim2:lim3)
#define FULL(v) ((v)==0?full0:(v)==1?full1:(v)==2?full2:full3)

// 4 voxels per block, 256 threads / 4 waves. Tiles 3v..3v+2 = voxel v.
__global__ __launch_bounds__(256, 4) void vfe_fused(
    const float* __restrict__ feat,
    const int* __restrict__ nvox,
    const void* __restrict__ ws,
    float* __restrict__ out,
    int K)
{
    __shared__ __align__(16) ushort sX0bf[192][8];          // x0 rows, bf16 masked
    __shared__ __align__(16) ushort sAfrag[12 * 16 * 24];   // h1: [tile][row16][chan pad24]
    __shared__ __align__(16) ushort sBfrag[12 * 2 * 64 * 8];// h2, fragment order (R8 layout)
    __shared__ __align__(16) ushort sAgg1bf[4][16];
    __shared__ __align__(16) ushort sAgg2bf[4][64];

    const ushort* w3p = (const ushort*)ws;
    const ushort* w2p = (const ushort*)((const char*)ws + W2P_OFF);
    const ushort* w1p = (const ushort*)((const char*)ws + W1P_OFF);
    const float*  bb1 = (const float*)((const char*)ws + B1_OFF);
    const float*  bb2 = (const float*)((const char*)ws + B2_OFF);
    const float*  bb3 = (const float*)((const char*)ws + B3_OFF);

    const int tid  = threadIdx.x;
    const int lane = tid & 63;
    const int w    = tid >> 6;
    const int g    = lane >> 4;
    const int m15  = lane & 15;
    const int kA   = blockIdx.x * 4;

    int kk0 = kA, kk1 = min(kA+1, K-1), kk2 = min(kA+2, K-1), kk3 = min(kA+3, K-1);
    int nv0 = __builtin_amdgcn_readfirstlane(nvox[kk0]);
    int nv1 = __builtin_amdgcn_readfirstlane(nvox[kk1]);
    int nv2 = __builtin_amdgcn_readfirstlane(nvox[kk2]);
    int nv3 = __builtin_amdgcn_readfirstlane(nvox[kk3]);
    const int lim0=(nv0+15)>>4, lim1=(nv1+15)>>4, lim2=(nv2+15)>>4, lim3=(nv3+15)>>4;
    const int full0=nv0>>4, full1=nv1>>4, full2=nv2>>4, full3=nv3>>4;

    union U8 { bf16x8 v; unsigned u[4]; };

    // ---- B-fragment preloads (L2-hot) ----
    const bf16x8 b1f   = *(const bf16x8*)(w1p + (size_t)lane * 8);
    const bf16x8 w2lof = *(const bf16x8*)(w2p + (size_t)((0 * 4 + w) * 64 + lane) * 8);
    const bf16x8 w2hif = *(const bf16x8*)(w2p + (size_t)((1 * 4 + w) * 64 + lane) * 8);
    bf16x8 b3f[2][4];
    #pragma unroll
    for (int nt = 0; nt < 2; ++nt)
        #pragma unroll
        for (int ks = 0; ks < 4; ++ks)
            b3f[nt][ks] = *(const bf16x8*)(w3p + (size_t)(((w * 2 + nt) * 4 + ks) * 64 + lane) * 8);

    // ---- stage 0: wave w -> voxel w (all 4 waves busy) ----
    {
        const int kkw = (w==0)?kk0:(w==1)?kk1:(w==2)?kk2:kk3;
        const int nvw = (w==0)?nv0:(w==1)?nv1:(w==2)?nv2:nv3;
        float4 f = make_float4(0.f, 0.f, 0.f, 0.f);
        if (lane < 48)
            f = *reinterpret_cast<const float4*>(feat + ((size_t)kkw * 48 + lane) * 4);
        float sx = f.x, sy = f.y, sz = f.z;
        #pragma unroll
        for (int d = 1; d < 64; d <<= 1) {
            sx += __shfl_xor(sx, d);
            sy += __shfl_xor(sy, d);
            sz += __shfl_xor(sz, d);
        }
        const float inv = 1.f / (float)nvw;
        if (lane < 48) {
            const float msk = (lane < nvw) ? 1.f : 0.f;
            const float dd = sqrtf(f.x * f.x + f.y * f.y + f.z * f.z);
            U8 a;
            a.u[0] = cvtpk(f.x * msk, f.y * msk);
            a.u[1] = cvtpk(f.z * msk, f.w * msk);
            a.u[2] = cvtpk((f.x - sx * inv) * msk, (f.y - sy * inv) * msk);
            a.u[3] = cvtpk((f.z - sz * inv) * msk, dd * msk);
            *reinterpret_cast<bf16x8*>(&sX0bf[w * 48 + lane][0]) = a.v;
        }
    }
    __syncthreads();

    // ---- layer 1 MFMA: wave w owns voxel w's 3 tiles; agg1 reduced in-wave ----
    {
        const float bb1u = bb1[m15];
        const int limw = (w==0)?lim0:(w==1)?lim1:(w==2)?lim2:lim3;
        float pmax = fmaxf(bb1u, 0.f);   // analytic masked-row term (nv<48 always)
        #pragma unroll
        for (int s = 0; s < 3; ++s) {
            if (s < limw) {
                const bf16x8 af = *(const bf16x8*)&sX0bf[w * 48 + s * 16 + m15][0];
                f32x4 ci = {bb1u, bb1u, bb1u, bb1u};
                f32x4 acc = __builtin_amdgcn_mfma_f32_16x16x32_bf16(af, b1f, ci, 0, 0, 0);
                #pragma unroll
                for (int r = 0; r < 4; ++r) {
                    const float h = fmaxf(acc[r], 0.f);
                    pmax = fmaxf(pmax, h);
                    sAfrag[((w * 3 + s) * 16 + g * 4 + r) * 24 + m15] = f2bf(h);  // unmasked
                }
            }
        }
        pmax = fmaxf(pmax, __shfl_xor(pmax, 16));
        pmax = fmaxf(pmax, __shfl_xor(pmax, 32));
        if (g == 0) sAgg1bf[w][m15] = f2bf(pmax);
    }
    __syncthreads();

    // ---- z2-fold MFMA: A rows cycle voxels (m15&3) -> C reg r = init for voxel r ----
    const int col2 = w * 16 + m15;
    const float bb2c = bb2[col2];
    f32x4 z2acc;
    {
        const bf16x8 az2 = *(const bf16x8*)&sAgg1bf[m15 & 3][(g & 1) * 8];
        f32x4 ci = {bb2c, bb2c, bb2c, bb2c};
        z2acc = __builtin_amdgcn_mfma_f32_16x16x32_bf16(az2, w2hif, ci, 0, 0, 0);
    }

    // ---- layer 2 MFMA in two 6-tile halves (C-init = bb2+z2) ----
    {
        const int ks = col2 >> 5, gp = (col2 >> 3) & 3, e = col2 & 7;
        #pragma unroll
        for (int vg = 0; vg < 2; ++vg) {
            f32x4 acc2[6];
            #pragma unroll
            for (int j = 0; j < 6; ++j) {
                const int tt = vg * 6 + j;
                const int vox = vg * 2 + j / 3;
                const int mtl = j % 3;
                if (mtl < LIM(vox)) {
                    const bf16x8 af = *(const bf16x8*)&sAfrag[(tt * 16 + m15) * 24 + (g & 1) * 8];
                    const float ci = z2acc[vox];
                    f32x4 c = {ci, ci, ci, ci};
                    acc2[j] = __builtin_amdgcn_mfma_f32_16x16x32_bf16(af, w2lof, c, 0, 0, 0);
                }
            }
            float mxP = fmaxf(bb2c, 0.f);   // voxel vg*2   (analytic masked-row term)
            float mxQ = fmaxf(bb2c, 0.f);   // voxel vg*2+1
            #pragma unroll
            for (int j = 0; j < 6; ++j) {
                const int tt = vg * 6 + j;
                const int vox = vg * 2 + j / 3;
                const int mtl = j % 3;
                if (mtl < LIM(vox)) {
                    float h[4];
                    #pragma unroll
                    for (int r = 0; r < 4; ++r) {
                        h[r] = fmaxf(acc2[j][r], 0.f);
                        sBfrag[((tt * 2 + ks) * 64 + gp * 16 + (g * 4 + r)) * 8 + e] = f2bf(h[r]);
                    }
                    if (mtl < FULL(vox)) {
                        const float t01 = fmaxf(h[0], h[1]), t23 = fmaxf(h[2], h[3]);
                        if (j < 3) mxP = fmaxf(mxP, fmaxf(t01, t23));
                        else       mxQ = fmaxf(mxQ, fmaxf(t01, t23));
                    } else {
                        #pragma unroll
                        for (int r = 0; r < 4; ++r) {
                            if (mtl * 16 + g * 4 + r < NV(vox)) {
                                if (j < 3) mxP = fmaxf(mxP, h[r]);
                                else       mxQ = fmaxf(mxQ, h[r]);
                            }
                        }
                    }
                }
            }
            mxP = fmaxf(mxP, __shfl_xor(mxP, 16));
            mxP = fmaxf(mxP, __shfl_xor(mxP, 32));
            mxQ = fmaxf(mxQ, __shfl_xor(mxQ, 16));
            mxQ = fmaxf(mxQ, __shfl_xor(mxQ, 32));
            if (g == 0) {
                sAgg2bf[vg * 2 + 0][col2] = f2bf(mxP);
                sAgg2bf[vg * 2 + 1][col2] = f2bf(mxQ);
            }
        }
    }
    __syncthreads();

    // ---- z3-fold (C-init = bb3; A rows cycle voxels) -> i3[nt][v] ----
    f32x4 i3[2];
    #pragma unroll
    for (int nt = 0; nt < 2; ++nt) {
        const float bb3c = bb3[(w * 2 + nt) * 16 + m15];
        f32x4 z = {bb3c, bb3c, bb3c, bb3c};
        #pragma unroll
        for (int ks2 = 0; ks2 < 2; ++ks2) {
            const bf16x8 af = *(const bf16x8*)&sAgg2bf[m15 & 3][ks2 * 32 + g * 8];
            z = __builtin_amdgcn_mfma_f32_16x16x32_bf16(af, b3f[nt][2 + ks2], z, 0, 0, 0);
        }
        i3[nt] = z;
    }

    // ---- layer 3 MFMA: 2 passes x two 6-tile halves (C-init = bb3+z3) ----
    #pragma unroll
    for (int pass = 0; pass < 2; ++pass) {
        const int col = (w * 2 + pass) * 16 + m15;
        #pragma unroll
        for (int vg = 0; vg < 2; ++vg) {
            f32x4 acc3[6];
            #pragma unroll
            for (int j = 0; j < 6; ++j) {
                const int tt = vg * 6 + j;
                const int vox = vg * 2 + j / 3;
                const int mtl = j % 3;
                if (mtl < LIM(vox)) {
                    const bf16x8 af0 = *(const bf16x8*)&sBfrag[((tt * 2 + 0) * 64 + lane) * 8];
                    const bf16x8 af1 = *(const bf16x8*)&sBfrag[((tt * 2 + 1) * 64 + lane) * 8];
                    const float ci = i3[pass][vox];
                    f32x4 c = {ci, ci, ci, ci};
                    acc3[j] = __builtin_amdgcn_mfma_f32_16x16x32_bf16(af0, b3f[pass][0], c, 0, 0, 0);
                    acc3[j] = __builtin_amdgcn_mfma_f32_16x16x32_bf16(af1, b3f[pass][1], acc3[j], 0, 0, 0);
                }
            }
            float mxP = 0.f, mxQ = 0.f;   // relu folded into fmax (mx >= 0)
            #pragma unroll
            for (int j = 0; j < 6; ++j) {
                const int vox = vg * 2 + j / 3;
                const int mtl = j % 3;
                if (mtl < FULL(vox)) {
                    const float t01 = fmaxf(acc3[j][0], acc3[j][1]);
                    const float t23 = fmaxf(acc3[j][2], acc3[j][3]);
                    if (j < 3) mxP = fmaxf(mxP, fmaxf(t01, t23));
                    else       mxQ = fmaxf(mxQ, fmaxf(t01, t23));
                } else if (mtl < LIM(vox)) {
                    #pragma unroll
                    for (int r = 0; r < 4; ++r) {
                        if (mtl * 16 + g * 4 + r < NV(vox)) {
                            if (j < 3) mxP = fmaxf(mxP, acc3[j][r]);
                            else       mxQ = fmaxf(mxQ, acc3[j][r]);
                        }
                    }
                }
            }
            mxP = fmaxf(mxP, __shfl_xor(mxP, 16));
            mxP = fmaxf(mxP, __shfl_xor(mxP, 32));
            mxQ = fmaxf(mxQ, __shfl_xor(mxQ, 16));
            mxQ = fmaxf(mxQ, __shfl_xor(mxQ, 32));
            if (g == (vg * 2 + 0) && (kA + vg * 2 + 0) < K) out[(size_t)(kA + vg * 2 + 0) * 128 + col] = mxP;
            if (g == (vg * 2 + 1) && (kA + vg * 2 + 1) < K) out[(size_t)(kA + vg * 2 + 1) * 128 + col] = mxQ;
        }
    }
}

extern "C" void kernel_launch(void* const* d_in, const int* in_sizes, int n_in,
                              void* d_out, int out_size, void* d_ws, size_t ws_size,
                              hipStream_t stream) {
    const float* feat = (const float*)d_in[0];
    const int*   nvx  = (const int*)d_in[1];
    const float* w1 = (const float*)d_in[3];
    const float* b1 = (const float*)d_in[4];
    const float* g1 = (const float*)d_in[5];
    const float* be1= (const float*)d_in[6];
    const float* m1 = (const float*)d_in[7];
    const float* v1 = (const float*)d_in[8];
    const float* w2 = (const float*)d_in[9];
    const float* b2 = (const float*)d_in[10];
    const float* g2 = (const float*)d_in[11];
    const float* be2= (const float*)d_in[12];
    const float* m2 = (const float*)d_in[13];
    const float* v2 = (const float*)d_in[14];
    const float* w3 = (const float*)d_in[15];
    const float* b3 = (const float*)d_in[16];
    const float* g3 = (const float*)d_in[17];
    const float* be3= (const float*)d_in[18];
    const float* m3 = (const float*)d_in[19];
    const float* v3 = (const float*)d_in[20];
    float* out = (float*)d_out;

    const int K = in_sizes[1];

    vfe_prep<<<84, 256, 0, stream>>>(w1,b1,g1,be1,m1,v1, w2,b2,g2,be2,m2,v2,
                                     w3,b3,g3,be3,m3,v3, d_ws);
    vfe_fused<<<(K + 3) / 4, 256, 0, stream>>>(feat, nvx, d_ws, out, K);
}